// Round 11
// baseline (136.424 us; speedup 1.0000x reference)
//
#include <hip/hip_runtime.h>
#include <math.h>
#include <stdint.h>

// Shapes (fixed by the problem)
constexpr int Bc = 16, Nn = 1024, Cc = 256, Hh = 4;
constexpr int Mrows = Bc * Nn;          // 16384
constexpr float EPSV = 1e-5f;

typedef __attribute__((ext_vector_type(4))) float f32x4;
typedef __attribute__((ext_vector_type(8))) short bf16x8;

__device__ inline float wave_reduce_sum(float v) {
#pragma unroll
  for (int m = 32; m >= 1; m >>= 1) v += __shfl_xor(v, m);
  return v;
}

__device__ inline short f2bf(float f) {
  uint32_t u = __builtin_bit_cast(uint32_t, f);
  u = (u + 0x7fffu + ((u >> 16) & 1u)) >> 16;  // RNE
  return (short)u;
}
__device__ inline float bf2f(short s) {
  uint32_t u = ((uint32_t)(uint16_t)s) << 16;
  return __builtin_bit_cast(float, u);
}

// branch-free tanh-form GELU: x * sigmoid(2u), u = sqrt(2/pi)*(x + 0.044715 x^3)
__device__ inline float gelu_fast(float x) {
  float x2 = x * x;
  float u = x * (0.7978845608028654f + 0.0356774081f * x2);
  float e = __builtin_amdgcn_exp2f(u * 2.8853900817779268f);  // exp(2u)
  return x * (1.f - __builtin_amdgcn_rcpf(e + 1.f));
}

#define GLDS(gptr, lptr)                                             \
  __builtin_amdgcn_global_load_lds(                                  \
      (const __attribute__((address_space(1))) void*)(gptr),         \
      (__attribute__((address_space(3))) void*)(lptr), 16, 0, 0)

// ---------------- fp32 -> bf16 weight conversion (all 4 weights, one launch) ----
__global__ __launch_bounds__(256)
void cvt_all(const float* __restrict__ s0, short* __restrict__ d0,   // 192 blk
             const float* __restrict__ s1, short* __restrict__ d1,   //  64 blk
             const float* __restrict__ s2, short* __restrict__ d2,   // 256 blk
             const float* __restrict__ s3, short* __restrict__ d3) { // 256 blk
  int bid = blockIdx.x;
  const float* s;
  short* d;
  int base;
  if (bid < 192)      { s = s0; d = d0; base = bid; }
  else if (bid < 256) { s = s1; d = d1; base = bid - 192; }
  else if (bid < 512) { s = s2; d = d2; base = bid - 256; }
  else                { s = s3; d = d3; base = bid - 512; }
  int i = (base * 256 + threadIdx.x) * 4;
  float4 v = *(const float4*)(s + i);
  short4 o;
  o.x = f2bf(v.x); o.y = f2bf(v.y); o.z = f2bf(v.z); o.w = f2bf(v.w);
  *(short4*)(d + i) = o;
}

// ---------------- LayerNorm: one wave per row of 256, bf16 out ----------------
__global__ __launch_bounds__(256)
void ln_kernel(const float* __restrict__ x, const float* __restrict__ g,
               const float* __restrict__ b, short* __restrict__ h) {
  int row = blockIdx.x * 4 + (threadIdx.x >> 6);
  int lane = threadIdx.x & 63;
  const float4* xr = (const float4*)(x + (size_t)row * Cc);
  float4 v = xr[lane];
  float s = v.x + v.y + v.z + v.w;
  float sq = v.x * v.x + v.y * v.y + v.z * v.z + v.w * v.w;
  s = wave_reduce_sum(s);
  sq = wave_reduce_sum(sq);
  float mean = s * (1.f / Cc);
  float var = sq * (1.f / Cc) - mean * mean;
  float inv = rsqrtf(var + EPSV);
  float4 gg = ((const float4*)g)[lane];
  float4 bb = ((const float4*)b)[lane];
  short4 o;
  o.x = f2bf((v.x - mean) * inv * gg.x + bb.x);
  o.y = f2bf((v.y - mean) * inv * gg.y + bb.y);
  o.z = f2bf((v.z - mean) * inv * gg.z + bb.z);
  o.w = f2bf((v.w - mean) * inv * gg.w + bb.w);
  *(short4*)(h + (size_t)row * Cc + lane * 4) = o;
}

// ---------------- QKV GEMM, 2-phase pipelined, packed scatter ----------------
__global__ __launch_bounds__(256)
void qkv_mfma(const short* __restrict__ A, const short* __restrict__ Bw,
              const float* __restrict__ bias, short* __restrict__ qkp,
              short* __restrict__ vtp) {
  __shared__ __align__(16) short As[2][128 * 64];
  __shared__ __align__(16) short Bs[2][128 * 64];
  int t = threadIdx.x;
  int w = t >> 6, lane = t & 63;
  int wm = w >> 1, wn = w & 1;
  int l16 = lane & 15, lhi = lane >> 4;
  int m0 = blockIdx.y * 128, n0 = blockIdx.x * 128;
  const bool vblk = (n0 >= 512);
  f32x4 acc[4][4] = {};

  // prologue: stage tile 0 into buf 0
#pragma unroll
  for (int i = 0; i < 4; ++i) {
    int cc = i * 256 + t;
    int r = cc >> 3, sl = cc & 7, ssl = sl ^ (r & 7);
    GLDS(A + (size_t)(m0 + r) * 256 + ssl * 8, &As[0][cc * 8]);
    GLDS(Bw + (size_t)(n0 + r) * 256 + ssl * 8, &Bs[0][cc * 8]);
  }

  int cur = 0;
  for (int k0 = 0; k0 < 256; k0 += 64, cur ^= 1) {
    asm volatile("s_waitcnt vmcnt(0)" ::: "memory");
    __syncthreads();  // tile k ready; buf[cur^1] free (prev compute done)
    int kn = k0 + 64;
    if (kn < 256) {
      int nxt = cur ^ 1;
#pragma unroll
      for (int i = 0; i < 4; ++i) {
        int cc = i * 256 + t;
        int r = cc >> 3, sl = cc & 7, ssl = sl ^ (r & 7);
        GLDS(A + (size_t)(m0 + r) * 256 + kn + ssl * 8, &As[nxt][cc * 8]);
        GLDS(Bw + (size_t)(n0 + r) * 256 + kn + ssl * 8, &Bs[nxt][cc * 8]);
      }
    }
#pragma unroll
    for (int ks = 0; ks < 2; ++ks) {
      bf16x8 af[4], bg[4];
#pragma unroll
      for (int mi = 0; mi < 4; ++mi) {
        int row = wm * 64 + mi * 16 + l16;
        af[mi] = *(const bf16x8*)&As[cur][row * 64 + ((ks * 32 + lhi * 8) ^ ((row & 7) << 3))];
      }
#pragma unroll
      for (int ni = 0; ni < 4; ++ni) {
        int row = wn * 64 + ni * 16 + l16;
        bg[ni] = *(const bf16x8*)&Bs[cur][row * 64 + ((ks * 32 + lhi * 8) ^ ((row & 7) << 3))];
      }
      if (!vblk) {
#pragma unroll
        for (int mi = 0; mi < 4; ++mi)
#pragma unroll
          for (int ni = 0; ni < 4; ++ni)
            acc[mi][ni] = __builtin_amdgcn_mfma_f32_16x16x32_bf16(
                af[mi], bg[ni], acc[mi][ni], 0, 0, 0);
      } else {
        // swapped: C' = C^T (rows of frag = n, cols = m)
#pragma unroll
        for (int mi = 0; mi < 4; ++mi)
#pragma unroll
          for (int ni = 0; ni < 4; ++ni)
            acc[mi][ni] = __builtin_amdgcn_mfma_f32_16x16x32_bf16(
                bg[ni], af[mi], acc[mi][ni], 0, 0, 0);
      }
    }
  }

  if (!vblk) {
    const bool isq = (n0 < 256);
#pragma unroll
    for (int mi = 0; mi < 4; ++mi) {
      int mbase = m0 + wm * 64 + mi * 16 + lhi * 4;
#pragma unroll
      for (int ni = 0; ni < 4; ++ni) {
        int n = n0 + wn * 64 + ni * 16 + l16;
        int s = n >> 8, hh = (n >> 6) & 3, d = n & 63;
        float bv = bias[n];
#pragma unroll
        for (int r = 0; r < 4; ++r) {
          int m = mbase + r;
          int b = m >> 10, rw = m & 1023;
          float v = acc[mi][ni][r] + bv;
          if (isq) v *= 0.125f;
          qkp[(size_t)s * 4194304 + (((size_t)(b * 4 + hh)) * 1024 + rw) * 64 + d] = f2bf(v);
        }
      }
    }
  } else {
#pragma unroll
    for (int mi = 0; mi < 4; ++mi) {
#pragma unroll
      for (int ni = 0; ni < 4; ++ni) {
#pragma unroll
        for (int r = 0; r < 4; ++r) {
          int n = n0 + wn * 64 + ni * 16 + lhi * 4 + r;   // 512..767
          int hh = (n >> 6) & 3, d = n & 63;
          int m = m0 + wm * 64 + mi * 16 + l16;
          int b = m >> 10, rw = m & 1023;
          float v = acc[mi][ni][r] + bias[n];
          vtp[(((size_t)(b * 4 + hh)) * 64 + d) * 1024 + rw] = f2bf(v);
        }
      }
    }
  }
}

// ---------------- mean over rows of v^T[bh][d][row] -> bf16[bh][d] ----------------
__global__ __launch_bounds__(256)
void vmean_kernel(const short* __restrict__ vt, short* __restrict__ vmb) {
  __shared__ float part[64][4];
  int bh = blockIdx.x;
  int d = threadIdx.x >> 2, seg = threadIdx.x & 3;
  const short* p = vt + (size_t)bh * 65536 + (size_t)d * 1024 + seg * 256;
  float s = 0.f;
  for (int i = 0; i < 256; i += 8) {
    bf16x8 v = *(const bf16x8*)(p + i);
#pragma unroll
    for (int j = 0; j < 8; ++j) s += bf2f(v[j]);
  }
  part[d][seg] = s;
  __syncthreads();
  if (threadIdx.x < 64) {
    int dd = threadIdx.x;
    float tot = part[dd][0] + part[dd][1] + part[dd][2] + part[dd][3];
    vmb[bh * 64 + dd] = f2bf(tot * (1.f / 1024.f));
  }
}

// ---------------- MFMA flash attention, KVBLK=128, split-K over blockIdx.z -------
// Block = 64 q-rows of one (b,h); 4 waves, wave w owns rows w*16..w*16+15.
// KV tiles are 128 wide (half the iterations of the r6 64-wide version at
// ~fixed per-iteration latency). tiles_per_split is in 128-tile units.
// LDS = 32+32+16 = 80KB exactly -> 2 blocks/CU (vmb read direct, no vms stage).
// Fixed-reference softmax (M=12): partials additive across splits.
__global__ __launch_bounds__(256)
void fattn_mfma(const short* __restrict__ qpk, const short* __restrict__ kpk,
                const short* __restrict__ vt, const float* __restrict__ Kmat,
                const int* __restrict__ n1, const int* __restrict__ n2,
                const short* __restrict__ vmb, short* __restrict__ o,
                float* __restrict__ pO, float* __restrict__ pL,
                int tiles_per_split) {
  int bh = blockIdx.y, b = bh >> 2, hh = bh & 3;
  int qt = blockIdx.x;
  int row0 = qt * 64;
  int sp = blockIdx.z;
  int nc = n1[b] * n2[b];
  int t = threadIdx.x;
  if (row0 >= nc) {
    // fully-masked rows: scores identical in fp32 -> uniform softmax -> mean(v)
    if (sp == 0) {
      for (int idx = t; idx < 4096; idx += 256) {
        int r = idx >> 6, d = idx & 63;
        o[((size_t)(b * 1024 + row0 + r)) * 256 + hh * 64 + d] = vmb[bh * 64 + d];
      }
    }
    return;
  }
  int ntiles = (nc + 127) >> 7;
  int nsp = (ntiles + tiles_per_split - 1) / tiles_per_split;
  int jt0 = sp * tiles_per_split;
  if (jt0 >= ntiles) return;
  int jstart = jt0 * 128;
  int jend = min(jstart + tiles_per_split * 128, nc);
  const bool final_out = (nsp == 1);

  __shared__ __align__(16) short Ks[2][128 * 64];  // 32 KB
  __shared__ __align__(16) short Vs[2][64 * 128];  // 32 KB
  __shared__ __align__(16) short Ps[64 * 128];     // 16 KB
  int w = t >> 6, lane = t & 63, l16 = lane & 15, lhi = lane >> 4;

  constexpr float LOG2E = 1.4426950408889634f;
  constexpr float MREF = 12.0f;  // fixed softmax reference

  // Q fragments (q pre-scaled by 0.125 at QKV epilogue)
  const short* qb = qpk + (size_t)bh * 65536 + (size_t)(row0 + w * 16 + l16) * 64;
  bf16x8 qf0 = *(const bf16x8*)(qb + lhi * 8);
  bf16x8 qf1 = *(const bf16x8*)(qb + 32 + lhi * 8);

  f32x4 accO[4] = {};
  float lsum[4] = {};
  const float* Kb = Kmat + (size_t)b * 1048576 + (size_t)(row0 + w * 16) * 1024;

  f32x4 kvp[8];  // bias for CURRENT tile, prefetched one tile ahead

  // ---- prologue: stage first tile (K: 128x64, V: 64x128), prefetch its bias ----
#pragma unroll
  for (int i = 0; i < 4; ++i) {
    int cc = i * 256 + t;
    int rk = cc >> 3, slk = cc & 7, sslk = slk ^ (rk & 7);
    GLDS(kpk + (size_t)bh * 65536 + (size_t)(jstart + rk) * 64 + sslk * 8, &Ks[0][cc * 8]);
    int rv = cc >> 4, slv = cc & 15, sslv = slv ^ (rv & 7);
    GLDS(vt + (size_t)bh * 65536 + (size_t)rv * 1024 + jstart + sslv * 8, &Vs[0][cc * 8]);
  }
#pragma unroll
  for (int ni = 0; ni < 8; ++ni)
#pragma unroll
    for (int r = 0; r < 4; ++r)
      kvp[ni][r] =
          (Kb[(size_t)(lhi * 4 + r) * 1024 + jstart + ni * 16 + l16] - MREF) * LOG2E;

  int cur = 0;
  for (int j0 = jstart; j0 < jend; j0 += 128, cur ^= 1) {
    asm volatile("s_waitcnt vmcnt(0)" ::: "memory");
    __syncthreads();  // tile j ready; buf[cur^1] free

    int jn = j0 + 128;
    if (jn < jend) {
      int nxt = cur ^ 1;
#pragma unroll
      for (int i = 0; i < 4; ++i) {
        int cc = i * 256 + t;
        int rk = cc >> 3, slk = cc & 7, sslk = slk ^ (rk & 7);
        GLDS(kpk + (size_t)bh * 65536 + (size_t)(jn + rk) * 64 + sslk * 8, &Ks[nxt][cc * 8]);
        int rv = cc >> 4, slv = cc & 15, sslv = slv ^ (rv & 7);
        GLDS(vt + (size_t)bh * 65536 + (size_t)rv * 1024 + jn + sslv * 8, &Vs[nxt][cc * 8]);
      }
    }

    // QK^T: S[q=16 rows of wave][128 cols]
    f32x4 accS[8] = {};
#pragma unroll
    for (int ks = 0; ks < 2; ++ks) {
#pragma unroll
      for (int ni = 0; ni < 8; ++ni) {
        int row = ni * 16 + l16;
        bf16x8 kf = *(const bf16x8*)&Ks[cur][row * 64 + (((ks * 4 + lhi) ^ (row & 7)) << 3)];
        accS[ni] = __builtin_amdgcn_mfma_f32_16x16x32_bf16(
            ks ? qf1 : qf0, kf, accS[ni], 0, 0, 0);
      }
    }

    // fixed-reference softmax: e = exp2(S*log2e + (K-M)*log2e), masked cols -> 0
#pragma unroll
    for (int ni = 0; ni < 8; ++ni) {
      bool valid = (j0 + ni * 16 + l16) < nc;
      int col16 = ni * 16 + l16;
#pragma unroll
      for (int r = 0; r < 4; ++r) {
        float e = __builtin_amdgcn_exp2f(fmaf(accS[ni][r], LOG2E, kvp[ni][r]));
        e = valid ? e : 0.f;
        lsum[r] += e;
        int prow = w * 16 + lhi * 4 + r;
        Ps[prow * 128 + ((((col16 >> 3) ^ (prow & 7)) << 3) | (col16 & 7))] = f2bf(e);
      }
    }

    // prefetch next tile's bias now (kvp free; arrives under PV + next QK^T)
    if (jn < jend) {
#pragma unroll
      for (int ni = 0; ni < 8; ++ni)
#pragma unroll
        for (int r = 0; r < 4; ++r)
          kvp[ni][r] =
              (Kb[(size_t)(lhi * 4 + r) * 1024 + jn + ni * 16 + l16] - MREF) * LOG2E;
    }

    // PV: O[16 q][64 d] += P[16 q][128 k] @ Vt[d][k]^T  (Ps rows wave-private)
#pragma unroll
    for (int ks = 0; ks < 4; ++ks) {
      int prow = w * 16 + l16;
      bf16x8 pf = *(const bf16x8*)&Ps[prow * 128 + (((ks * 4 + lhi) ^ (prow & 7)) << 3)];
#pragma unroll
      for (int ni = 0; ni < 4; ++ni) {
        int vrow = ni * 16 + l16;
        bf16x8 vf = *(const bf16x8*)&Vs[cur][vrow * 128 + (((ks * 4 + lhi) ^ (vrow & 7)) << 3)];
        accO[ni] = __builtin_amdgcn_mfma_f32_16x16x32_bf16(pf, vf, accO[ni], 0, 0, 0);
      }
    }
  }

  // one-time denominator reduce over the 16-lane col group
#pragma unroll
  for (int r = 0; r < 4; ++r) {
    lsum[r] += __shfl_xor(lsum[r], 1);
    lsum[r] += __shfl_xor(lsum[r], 2);
    lsum[r] += __shfl_xor(lsum[r], 4);
    lsum[r] += __shfl_xor(lsum[r], 8);
  }

  if (final_out) {
    // epilogue: direct output
#pragma unroll
    for (int ni = 0; ni < 4; ++ni) {
#pragma unroll
      for (int r = 0; r < 4; ++r) {
        int row = row0 + w * 16 + lhi * 4 + r;
        int d = ni * 16 + l16;
        short ov;
        if (row < nc) ov = f2bf(accO[ni][r] * (1.f / lsum[r]));
        else ov = vmb[bh * 64 + d];
        o[((size_t)(b * 1024 + row)) * 256 + hh * 64 + d] = ov;
      }
    }
  } else {
    // write fp32 partials; combine kernel sums over splits (fixed order)
    float* po = pO + (((size_t)sp * 64 + bh) * 16 + qt) * 4096;
#pragma unroll
    for (int ni = 0; ni < 4; ++ni)
#pragma unroll
      for (int r = 0; r < 4; ++r)
        po[(w * 16 + lhi * 4 + r) * 64 + ni * 16 + l16] = accO[ni][r];
    if (l16 == 0) {
      float* pl = pL + (((size_t)sp * 64 + bh) * 16 + qt) * 64;
#pragma unroll
      for (int r = 0; r < 4; ++r) pl[w * 16 + lhi * 4 + r] = lsum[r];
    }
    // mean-fill rows >= nc handled once (split covering jstart==0)
    if (sp == 0) {
      for (int idx = t; idx < 4096; idx += 256) {
        int r = idx >> 6, d = idx & 63;
        int row = row0 + r;
        if (row >= nc)
          o[((size_t)(b * 1024 + row)) * 256 + hh * 64 + d] = vmb[bh * 64 + d];
      }
    }
  }
}

// ---------------- combine split-K partials -> bf16 output ----------------
__global__ __launch_bounds__(256)
void fattn_combine(const float* __restrict__ pO, const float* __restrict__ pL,
                   const int* __restrict__ n1, const int* __restrict__ n2,
                   short* __restrict__ o, int tiles_per_split) {
  int bh = blockIdx.y, b = bh >> 2, hh = bh & 3;
  int qt = blockIdx.x;
  int row0 = qt * 64;
  int nc = n1[b] * n2[b];
  if (row0 >= nc) return;
  int ntiles = (nc + 127) >> 7;   // 128-wide KV tiles (must match fattn)
  int nsp = (ntiles + tiles_per_split - 1) / tiles_per_split;
  if (nsp < 2) return;  // fattn wrote final output

  int t = threadIdx.x;
  int q = t >> 2, ds = (t & 3) * 16;
  int row = row0 + q;
  if (row >= nc) return;

  const size_t spstrideO = (size_t)64 * 16 * 4096;
  const size_t spstrideL = (size_t)64 * 16 * 64;
  const float* baseO = pO + ((size_t)bh * 16 + qt) * 4096 + q * 64 + ds;
  const float* baseL = pL + ((size_t)bh * 16 + qt) * 64 + q;

  f32x4 s[4] = {};
  float L = 0.f;
  for (int sp = 0; sp < nsp; ++sp) {
    const float* p = baseO + sp * spstrideO;
#pragma unroll
    for (int i = 0; i < 4; ++i) s[i] += *(const f32x4*)(p + i * 4);
    L += baseL[sp * spstrideL];
  }
  float rl = 1.f / L;
  short* op = o + ((size_t)(b * 1024 + row)) * 256 + hh * 64 + ds;
#pragma unroll
  for (int i = 0; i < 4; ++i) {
    short4 ov;
    ov.x = f2bf(s[i][0] * rl);
    ov.y = f2bf(s[i][1] * rl);
    ov.z = f2bf(s[i][2] * rl);
    ov.w = f2bf(s[i][3] * rl);
    *(short4*)(op + i * 4) = ov;
  }
}

// ---------------- fused proj GEMM + residual + LayerNorm2 ----------------
__global__ __launch_bounds__(256)
void proj_ln_mfma(const short* __restrict__ A, const short* __restrict__ Bw,
                  const float* __restrict__ bias, const float* __restrict__ resid,
                  const float* __restrict__ g2, const float* __restrict__ b2,
                  float* __restrict__ Cf, short* __restrict__ h2) {
  __shared__ __align__(16) short As[2][64 * 64];    // 16 KB
  __shared__ __align__(16) short Bs[2][256 * 64];   // 64 KB
  int t = threadIdx.x;
  int w = t >> 6, lane = t & 63;
  int l16 = lane & 15, lhi = lane >> 4;
  int m0 = blockIdx.x * 64;
  constexpr int Kd = 256;
  f32x4 acc[4][4] = {};

  // prologue: stage tile 0
#pragma unroll
  for (int i = 0; i < 2; ++i) {
    int cc = i * 256 + t;
    int r = cc >> 3, sl = cc & 7, ssl = sl ^ (r & 7);
    GLDS(A + (size_t)(m0 + r) * Kd + ssl * 8, &As[0][cc * 8]);
  }
#pragma unroll
  for (int i = 0; i < 8; ++i) {
    int cc = i * 256 + t;
    int r = cc >> 3, sl = cc & 7, ssl = sl ^ (r & 7);
    GLDS(Bw + (size_t)r * Kd + ssl * 8, &Bs[0][cc * 8]);
  }

  int cur = 0;
  for (int k0 = 0; k0 < Kd; k0 += 64, cur ^= 1) {
    asm volatile("s_waitcnt vmcnt(0)" ::: "memory");
    __syncthreads();
    int kn = k0 + 64;
    if (kn < Kd) {
      int nxt = cur ^ 1;
#pragma unroll
      for (int i = 0; i < 2; ++i) {
        int cc = i * 256 + t;
        int r = cc >> 3, sl = cc & 7, ssl = sl ^ (r & 7);
        GLDS(A + (size_t)(m0 + r) * Kd + kn + ssl * 8, &As[nxt][cc * 8]);
      }
#pragma unroll
      for (int i = 0; i < 8; ++i) {
        int cc = i * 256 + t;
        int r = cc >> 3, sl = cc & 7, ssl = sl ^ (r & 7);
        GLDS(Bw + (size_t)r * Kd + kn + ssl * 8, &Bs[nxt][cc * 8]);
      }
    }
#pragma unroll
    for (int ks = 0; ks < 2; ++ks) {
      bf16x8 af[4], bg[4];
#pragma unroll
      for (int mi = 0; mi < 4; ++mi) {
        int row = mi * 16 + l16;
        af[mi] = *(const bf16x8*)&As[cur][row * 64 + ((ks * 32 + lhi * 8) ^ ((row & 7) << 3))];
      }
#pragma unroll
      for (int ni = 0; ni < 4; ++ni) {
        int row = w * 64 + ni * 16 + l16;
        bg[ni] = *(const bf16x8*)&Bs[cur][row * 64 + ((ks * 32 + lhi * 8) ^ ((row & 7) << 3))];
      }
#pragma unroll
      for (int mi = 0; mi < 4; ++mi)
#pragma unroll
        for (int ni = 0; ni < 4; ++ni)
          acc[mi][ni] = __builtin_amdgcn_mfma_f32_16x16x32_bf16(
              af[mi], bg[ni], acc[mi][ni], 0, 0, 0);
    }
  }

  // epilogue: v = acc + bias + resid; write fp32 out; keep v in acc
  float bv[4], gl[4], bl[4];
#pragma unroll
  for (int ni = 0; ni < 4; ++ni) {
    int n = w * 64 + ni * 16 + l16;
    bv[ni] = bias[n];
    gl[ni] = g2[n];
    bl[ni] = b2[n];
  }
#pragma unroll
  for (int mi = 0; mi < 4; ++mi)
#pragma unroll
    for (int ni = 0; ni < 4; ++ni) {
      int n = w * 64 + ni * 16 + l16;
#pragma unroll
      for (int r = 0; r < 4; ++r) {
        int m = m0 + mi * 16 + lhi * 4 + r;
        size_t idx = (size_t)m * 256 + n;
        float v = acc[mi][ni][r] + bv[ni] + resid[idx];
        acc[mi][ni][r] = v;
        Cf[idx] = v;
      }
    }

  // per-row stats: thread-local over ni, shuffle over l16, LDS across waves
  float s[4][4], qq[4][4];
#pragma unroll
  for (int mi = 0; mi < 4; ++mi)
#pragma unroll
    for (int r = 0; r < 4; ++r) {
      float a0 = acc[mi][0][r], a1 = acc[mi][1][r];
      float a2 = acc[mi][2][r], a3 = acc[mi][3][r];
      s[mi][r] = a0 + a1 + a2 + a3;
      qq[mi][r] = a0 * a0 + a1 * a1 + a2 * a2 + a3 * a3;
    }
#pragma unroll
  for (int off = 1; off <= 8; off <<= 1)
#pragma unroll
    for (int mi = 0; mi < 4; ++mi)
#pragma unroll
      for (int r = 0; r < 4; ++r) {
        s[mi][r] += __shfl_xor(s[mi][r], off);
        qq[mi][r] += __shfl_xor(qq[mi][r], off);
      }

  __syncthreads();  // all waves done reading As/Bs; safe to alias As
  float* partS = (float*)&As[0][0];   // [4 waves][64 rows]
  float* partQ = partS + 256;
  if (l16 == 0) {
#pragma unroll
    for (int mi = 0; mi < 4; ++mi)
#pragma unroll
      for (int r = 0; r < 4; ++r) {
        int row = mi * 16 + lhi * 4 + r;
        partS[w * 64 + row] = s[mi][r];
        partQ[w * 64 + row] = qq[mi][r];
      }
  }
  __syncthreads();

#pragma unroll
  for (int mi = 0; mi < 4; ++mi)
#pragma unroll
    for (int r = 0; r < 4; ++r) {
      int row = mi * 16 + lhi * 4 + r;
      float S = partS[row] + partS[64 + row] + partS[128 + row] + partS[192 + row];
      float Q = partQ[row] + partQ[64 + row] + partQ[128 + row] + partQ[192 + row];
      float mean = S * (1.f / 256.f);
      float var = Q * (1.f / 256.f) - mean * mean;
      float inv = rsqrtf(var + EPSV);
      int m = m0 + row;
#pragma unroll
      for (int ni = 0; ni < 4; ++ni) {
        int n = w * 64 + ni * 16 + l16;
        h2[(size_t)m * 256 + n] =
            f2bf((acc[mi][ni][r] - mean) * inv * gl[ni] + bl[ni]);
      }
    }
}

// ---------------- bf16 MFMA GEMM 128x128, 2-phase pipelined ----------------
template <bool GELU, bool RES, bool OUTF, bool OUTB>
__global__ __launch_bounds__(256)
void gemm_mfma(const short* __restrict__ A, const short* __restrict__ Bw,
               const float* __restrict__ bias, const float* __restrict__ resid,
               float* __restrict__ Cf, short* __restrict__ Cb,
               int M, int Nd, int Kd) {
  __shared__ __align__(16) short As[2][128 * 64];
  __shared__ __align__(16) short Bs[2][128 * 64];
  int t = threadIdx.x;
  int w = t >> 6, lane = t & 63;
  int wm = w >> 1, wn = w & 1;
  int l16 = lane & 15, lhi = lane >> 4;
  int m0 = blockIdx.y * 128, n0 = blockIdx.x * 128;
  f32x4 acc[4][4] = {};

  // prologue: stage tile 0 into buf 0
#pragma unroll
  for (int i = 0; i < 4; ++i) {
    int cc = i * 256 + t;
    int r = cc >> 3, sl = cc & 7, ssl = sl ^ (r & 7);
    GLDS(A + (size_t)(m0 + r) * Kd + ssl * 8, &As[0][cc * 8]);
    GLDS(Bw + (size_t)(n0 + r) * Kd + ssl * 8, &Bs[0][cc * 8]);
  }

  int cur = 0;
  for (int k0 = 0; k0 < Kd; k0 += 64, cur ^= 1) {
    asm volatile("s_waitcnt vmcnt(0)" ::: "memory");
    __syncthreads();  // tile k ready; buf[cur^1] free
    int kn = k0 + 64;
    if (kn < Kd) {
      int nxt = cur ^ 1;
#pragma unroll
      for (int i = 0; i < 4; ++i) {
        int cc = i * 256 + t;
        int r = cc >> 3, sl = cc & 7, ssl = sl ^ (r & 7);
        GLDS(A + (size_t)(m0 + r) * Kd + kn + ssl * 8, &As[nxt][cc * 8]);
        GLDS(Bw + (size_t)(n0 + r) * Kd + kn + ssl * 8, &Bs[nxt][cc * 8]);
      }
    }
#pragma unroll
    for (int ks = 0; ks < 2; ++ks) {
      bf16x8 af[4], bg[4];
#pragma unroll
      for (int mi = 0; mi < 4; ++mi) {
        int row = wm * 64 + mi * 16 + l16;
        af[mi] = *(const bf16x8*)&As[cur][row * 64 + ((ks * 32 + lhi * 8) ^ ((row & 7) << 3))];
      }
#pragma unroll
      for (int ni = 0; ni < 4; ++ni) {
        int row = wn * 64 + ni * 16 + l16;
        bg[ni] = *(const bf16x8*)&Bs[cur][row * 64 + ((ks * 32 + lhi * 8) ^ ((row & 7) << 3))];
      }
#pragma unroll
      for (int mi = 0; mi < 4; ++mi)
#pragma unroll
        for (int ni = 0; ni < 4; ++ni)
          acc[mi][ni] = __builtin_amdgcn_mfma_f32_16x16x32_bf16(
              af[mi], bg[ni], acc[mi][ni], 0, 0, 0);
    }
  }
#pragma unroll
  for (int mi = 0; mi < 4; ++mi) {
    int rbase = m0 + wm * 64 + mi * 16 + lhi * 4;
#pragma unroll
    for (int ni = 0; ni < 4; ++ni) {
      int n = n0 + wn * 64 + ni * 16 + l16;
      float bv = bias[n];
#pragma unroll
      for (int r = 0; r < 4; ++r) {
        int m = rbase + r;
        float v = acc[mi][ni][r] + bv;
        if (GELU) v = gelu_fast(v);
        size_t idx = (size_t)m * Nd + n;
        if (RES) v += resid[idx];
        if (OUTF) Cf[idx] = v;
        if (OUTB) Cb[idx] = f2bf(v);
      }
    }
  }
}

// ---------------- bf16 MFMA GEMM 64x128, 2-phase pipelined ----------------
template <bool GELU, bool RES, bool OUTF, bool OUTB>
__global__ __launch_bounds__(256)
void gemm64_mfma(const short* __restrict__ A, const short* __restrict__ Bw,
                 const float* __restrict__ bias, const float* __restrict__ resid,
                 float* __restrict__ Cf, short* __restrict__ Cb,
                 int M, int Nd, int Kd) {
  __shared__ __align__(16) short As[2][64 * 64];
  __shared__ __align__(16) short Bs[2][128 * 64];
  int t = threadIdx.x;
  int w = t >> 6, lane = t & 63;
  int l16 = lane & 15, lhi = lane >> 4;
  int m0 = blockIdx.y * 64, n0 = blockIdx.x * 128;
  f32x4 acc[4][2] = {};

  // prologue: stage tile 0 into buf 0
#pragma unroll
  for (int i = 0; i < 2; ++i) {
    int cc = i * 256 + t;
    int r = cc >> 3, sl = cc & 7, ssl = sl ^ (r & 7);
    GLDS(A + (size_t)(m0 + r) * Kd + ssl * 8, &As[0][cc * 8]);
  }
#pragma unroll
  for (int i = 0; i < 4; ++i) {
    int cc = i * 256 + t;
    int r = cc >> 3, sl = cc & 7, ssl = sl ^ (r & 7);
    GLDS(Bw + (size_t)(n0 + r) * Kd + ssl * 8, &Bs[0][cc * 8]);
  }

  int cur = 0;
  for (int k0 = 0; k0 < Kd; k0 += 64, cur ^= 1) {
    asm volatile("s_waitcnt vmcnt(0)" ::: "memory");
    __syncthreads();  // tile k ready; buf[cur^1] free
    int kn = k0 + 64;
    if (kn < Kd) {
      int nxt = cur ^ 1;
#pragma unroll
      for (int i = 0; i < 2; ++i) {
        int cc = i * 256 + t;
        int r = cc >> 3, sl = cc & 7, ssl = sl ^ (r & 7);
        GLDS(A + (size_t)(m0 + r) * Kd + kn + ssl * 8, &As[nxt][cc * 8]);
      }
#pragma unroll
      for (int i = 0; i < 4; ++i) {
        int cc = i * 256 + t;
        int r = cc >> 3, sl = cc & 7, ssl = sl ^ (r & 7);
        GLDS(Bw + (size_t)(n0 + r) * Kd + kn + ssl * 8, &Bs[nxt][cc * 8]);
      }
    }
#pragma unroll
    for (int ks = 0; ks < 2; ++ks) {
      bf16x8 af[4], bg[2];
#pragma unroll
      for (int mi = 0; mi < 4; ++mi) {
        int row = mi * 16 + l16;
        af[mi] = *(const bf16x8*)&As[cur][row * 64 + ((ks * 32 + lhi * 8) ^ ((row & 7) << 3))];
      }
#pragma unroll
      for (int ni = 0; ni < 2; ++ni) {
        int row = w * 32 + ni * 16 + l16;
        bg[ni] = *(const bf16x8*)&Bs[cur][row * 64 + ((ks * 32 + lhi * 8) ^ ((row & 7) << 3))];
      }
#pragma unroll
      for (int mi = 0; mi < 4; ++mi)
#pragma unroll
        for (int ni = 0; ni < 2; ++ni)
          acc[mi][ni] = __builtin_amdgcn_mfma_f32_16x16x32_bf16(
              af[mi], bg[ni], acc[mi][ni], 0, 0, 0);
    }
  }
#pragma unroll
  for (int mi = 0; mi < 4; ++mi) {
    int rbase = m0 + mi * 16 + lhi * 4;
#pragma unroll
    for (int ni = 0; ni < 2; ++ni) {
      int n = n0 + w * 32 + ni * 16 + l16;
      float bv = bias[n];
#pragma unroll
      for (int r = 0; r < 4; ++r) {
        int m = rbase + r;
        float v = acc[mi][ni][r] + bv;
        if (GELU) v = gelu_fast(v);
        size_t idx = (size_t)m * Nd + n;
        if (RES) v += resid[idx];
        if (OUTF) Cf[idx] = v;
        if (OUTB) Cb[idx] = f2bf(v);
      }
    }
  }
}

extern "C" void kernel_launch(void* const* d_in, const int* in_sizes, int n_in,
                              void* d_out, int out_size, void* d_ws, size_t ws_size,
                              hipStream_t stream) {
  const float* x      = (const float*)d_in[0];
  const float* Kmat   = (const float*)d_in[1];
  const int*   n1     = (const int*)d_in[2];
  const int*   n2     = (const int*)d_in[3];
  const float* qkv_w  = (const float*)d_in[4];
  const float* qkv_b  = (const float*)d_in[5];
  const float* proj_w = (const float*)d_in[6];
  const float* proj_b = (const float*)d_in[7];
  const float* ln1_g  = (const float*)d_in[8];
  const float* ln1_b  = (const float*)d_in[9];
  const float* ln2_g  = (const float*)d_in[10];
  const float* ln2_b  = (const float*)d_in[11];
  const float* fc1_w  = (const float*)d_in[12];
  const float* fc1_b  = (const float*)d_in[13];
  const float* fc2_w  = (const float*)d_in[14];
  const float* fc2_b  = (const float*)d_in[15];
  float* out = (float*)d_out;

  char* ws = (char*)d_ws;
  constexpr size_t MB = 1024 * 1024;
  // layout:
  //  [0,8): hb bf16 (LN1 out -> obuf attn out)
  //  [8,24): qkp bf16 (qpk at 8, kpk at 16); [24,32): vt bf16 [bh][d][row]
  //  [8,40): m1 bf16 (fc1 out; overlays qkp/vt AFTER attention)
  //  [40]: vmb ; [41..45): bf16 weights
  //  [48,116): split-K partial O fp32 (dead after combine) -> hb2 (LN2 out)
  //  [116,117): partial L fp32
  short* hb    = (short*)ws;
  short* qkp   = (short*)(ws + 8 * MB);
  short* vtp   = (short*)(ws + 24 * MB);
  short* m1    = (short*)(ws + 8 * MB);
  short* vmb   = (short*)(ws + 40 * MB);
  short* wqkv  = (short*)(ws + 41 * MB);
  short* wproj = (short*)(ws + 42 * MB);
  short* wfc1  = (short*)(ws + 43 * MB);
  short* wfc2  = (short*)(ws + 44 * MB);
  float* pO    = (float*)(ws + 48 * MB);
  float* pL    = (float*)(ws + 116 * MB);
  short* hb2   = (short*)(ws + 48 * MB);  // reuses pO region (dead by proj time)
  short* obuf  = hb;
  short* qpk   = qkp;
  short* kpk   = qkp + 4194304;

  const bool split = ws_size >= (size_t)118 * MB;

  // 0) all weights -> bf16 (single launch)
  cvt_all<<<dim3(768), 256, 0, stream>>>(qkv_w, wqkv, proj_w, wproj,
                                         fc1_w, wfc1, fc2_w, wfc2);
  // 1) h = LN1(x) -> bf16
  ln_kernel<<<dim3(Mrows / 4), 256, 0, stream>>>(x, ln1_g, ln1_b, hb);
  // 2) qkv GEMM -> packed bf16 q (x0.125), k [bh][row][d]; v^T [bh][d][row]
  qkv_mfma<<<dim3(6, 128), 256, 0, stream>>>(hb, wqkv, qkv_b, qkp, vtp);
  // 3) per-(b,h) mean of v
  vmean_kernel<<<dim3(Bc * Hh), 256, 0, stream>>>(vtp, vmb);
  // 4) MFMA flash attention -> obuf bf16 [B,N,C]
  //    KVBLK=128; split-K over z with 2 128-tiles per split (chain <= 2 iters)
  if (split) {
    fattn_mfma<<<dim3(Nn / 64, Bc * Hh, 4), 256, 0, stream>>>(
        qpk, kpk, vtp, Kmat, n1, n2, vmb, obuf, pO, pL, 2);
    fattn_combine<<<dim3(Nn / 64, Bc * Hh), 256, 0, stream>>>(
        pO, pL, n1, n2, obuf, 2);
  } else {
    fattn_mfma<<<dim3(Nn / 64, Bc * Hh, 1), 256, 0, stream>>>(
        qpk, kpk, vtp, Kmat, n1, n2, vmb, obuf, pO, pL, 8);
  }
  // 5+6) out = x + obuf @ proj_w^T + proj_b (fp32) AND hb2 = LN2(out) bf16, fused
  proj_ln_mfma<<<dim3(256), 256, 0, stream>>>(
      obuf, wproj, proj_b, x, ln2_g, ln2_b, out, hb2);
  // 7) m1 = GELU(hb2 @ fc1_w^T + fc1_b) -> bf16
  gemm_mfma<true, false, false, true><<<dim3(8, 128), 256, 0, stream>>>(
      hb2, wfc1, fc1_b, nullptr, nullptr, m1, Mrows, 1024, 256);
  // 8) out = out + m1 @ fc2_w^T + fc2_b (in-place residual) [64-row tiles]
  gemm64_mfma<false, true, true, false><<<dim3(2, 256), 256, 0, stream>>>(
      m1, wfc2, fc2_b, out, out, nullptr, Mrows, 256, 1024);
}

// Round 12
// 128.537 us; speedup vs baseline: 1.0614x; 1.0614x over previous
//
#include <hip/hip_runtime.h>
#include <math.h>
#include <stdint.h>

// Shapes (fixed by the problem)
constexpr int Bc = 16, Nn = 1024, Cc = 256, Hh = 4;
constexpr int Mrows = Bc * Nn;          // 16384
constexpr float EPSV = 1e-5f;

typedef __attribute__((ext_vector_type(4))) float f32x4;
typedef __attribute__((ext_vector_type(8))) short bf16x8;

__device__ inline float wave_reduce_sum(float v) {
#pragma unroll
  for (int m = 32; m >= 1; m >>= 1) v += __shfl_xor(v, m);
  return v;
}

__device__ inline short f2bf(float f) {
  uint32_t u = __builtin_bit_cast(uint32_t, f);
  u = (u + 0x7fffu + ((u >> 16) & 1u)) >> 16;  // RNE
  return (short)u;
}
__device__ inline float bf2f(short s) {
  uint32_t u = ((uint32_t)(uint16_t)s) << 16;
  return __builtin_bit_cast(float, u);
}

// branch-free tanh-form GELU: x * sigmoid(2u), u = sqrt(2/pi)*(x + 0.044715 x^3)
__device__ inline float gelu_fast(float x) {
  float x2 = x * x;
  float u = x * (0.7978845608028654f + 0.0356774081f * x2);
  float e = __builtin_amdgcn_exp2f(u * 2.8853900817779268f);  // exp(2u)
  return x * (1.f - __builtin_amdgcn_rcpf(e + 1.f));
}

#define GLDS(gptr, lptr)                                             \
  __builtin_amdgcn_global_load_lds(                                  \
      (const __attribute__((address_space(1))) void*)(gptr),         \
      (__attribute__((address_space(3))) void*)(lptr), 16, 0, 0)

// ------- prep: weight fp32->bf16 (blocks 0..767) + LN1 (blocks 768..4863) -------
__global__ __launch_bounds__(256)
void prep_kernel(const float* __restrict__ s0, short* __restrict__ d0,   // 192 blk
                 const float* __restrict__ s1, short* __restrict__ d1,   //  64 blk
                 const float* __restrict__ s2, short* __restrict__ d2,   // 256 blk
                 const float* __restrict__ s3, short* __restrict__ d3,   // 256 blk
                 const float* __restrict__ x, const float* __restrict__ g,
                 const float* __restrict__ b, short* __restrict__ h) {
  int bid = blockIdx.x;
  if (bid < 768) {
    const float* s;
    short* d;
    int base;
    if (bid < 192)      { s = s0; d = d0; base = bid; }
    else if (bid < 256) { s = s1; d = d1; base = bid - 192; }
    else if (bid < 512) { s = s2; d = d2; base = bid - 256; }
    else                { s = s3; d = d3; base = bid - 512; }
    int i = (base * 256 + threadIdx.x) * 4;
    float4 v = *(const float4*)(s + i);
    short4 o;
    o.x = f2bf(v.x); o.y = f2bf(v.y); o.z = f2bf(v.z); o.w = f2bf(v.w);
    *(short4*)(d + i) = o;
  } else {
    int row = (bid - 768) * 4 + (threadIdx.x >> 6);
    int lane = threadIdx.x & 63;
    const float4* xr = (const float4*)(x + (size_t)row * Cc);
    float4 v = xr[lane];
    float s = v.x + v.y + v.z + v.w;
    float sq = v.x * v.x + v.y * v.y + v.z * v.z + v.w * v.w;
    s = wave_reduce_sum(s);
    sq = wave_reduce_sum(sq);
    float mean = s * (1.f / Cc);
    float var = sq * (1.f / Cc) - mean * mean;
    float inv = rsqrtf(var + EPSV);
    float4 gg = ((const float4*)g)[lane];
    float4 bb = ((const float4*)b)[lane];
    short4 o;
    o.x = f2bf((v.x - mean) * inv * gg.x + bb.x);
    o.y = f2bf((v.y - mean) * inv * gg.y + bb.y);
    o.z = f2bf((v.z - mean) * inv * gg.z + bb.z);
    o.w = f2bf((v.w - mean) * inv * gg.w + bb.w);
    *(short4*)(h + (size_t)row * Cc + lane * 4) = o;
  }
}

// ---------------- QKV GEMM, 2-phase pipelined, packed scatter ----------------
__global__ __launch_bounds__(256)
void qkv_mfma(const short* __restrict__ A, const short* __restrict__ Bw,
              const float* __restrict__ bias, short* __restrict__ qkp,
              short* __restrict__ vtp) {
  __shared__ __align__(16) short As[2][128 * 64];
  __shared__ __align__(16) short Bs[2][128 * 64];
  int t = threadIdx.x;
  int w = t >> 6, lane = t & 63;
  int wm = w >> 1, wn = w & 1;
  int l16 = lane & 15, lhi = lane >> 4;
  int m0 = blockIdx.y * 128, n0 = blockIdx.x * 128;
  const bool vblk = (n0 >= 512);
  f32x4 acc[4][4] = {};

  // prologue: stage tile 0 into buf 0
#pragma unroll
  for (int i = 0; i < 4; ++i) {
    int cc = i * 256 + t;
    int r = cc >> 3, sl = cc & 7, ssl = sl ^ (r & 7);
    GLDS(A + (size_t)(m0 + r) * 256 + ssl * 8, &As[0][cc * 8]);
    GLDS(Bw + (size_t)(n0 + r) * 256 + ssl * 8, &Bs[0][cc * 8]);
  }

  int cur = 0;
  for (int k0 = 0; k0 < 256; k0 += 64, cur ^= 1) {
    asm volatile("s_waitcnt vmcnt(0)" ::: "memory");
    __syncthreads();  // tile k ready; buf[cur^1] free (prev compute done)
    int kn = k0 + 64;
    if (kn < 256) {
      int nxt = cur ^ 1;
#pragma unroll
      for (int i = 0; i < 4; ++i) {
        int cc = i * 256 + t;
        int r = cc >> 3, sl = cc & 7, ssl = sl ^ (r & 7);
        GLDS(A + (size_t)(m0 + r) * 256 + kn + ssl * 8, &As[nxt][cc * 8]);
        GLDS(Bw + (size_t)(n0 + r) * 256 + kn + ssl * 8, &Bs[nxt][cc * 8]);
      }
    }
#pragma unroll
    for (int ks = 0; ks < 2; ++ks) {
      bf16x8 af[4], bg[4];
#pragma unroll
      for (int mi = 0; mi < 4; ++mi) {
        int row = wm * 64 + mi * 16 + l16;
        af[mi] = *(const bf16x8*)&As[cur][row * 64 + ((ks * 32 + lhi * 8) ^ ((row & 7) << 3))];
      }
#pragma unroll
      for (int ni = 0; ni < 4; ++ni) {
        int row = wn * 64 + ni * 16 + l16;
        bg[ni] = *(const bf16x8*)&Bs[cur][row * 64 + ((ks * 32 + lhi * 8) ^ ((row & 7) << 3))];
      }
      if (!vblk) {
#pragma unroll
        for (int mi = 0; mi < 4; ++mi)
#pragma unroll
          for (int ni = 0; ni < 4; ++ni)
            acc[mi][ni] = __builtin_amdgcn_mfma_f32_16x16x32_bf16(
                af[mi], bg[ni], acc[mi][ni], 0, 0, 0);
      } else {
        // swapped: C' = C^T (rows of frag = n, cols = m)
#pragma unroll
        for (int mi = 0; mi < 4; ++mi)
#pragma unroll
          for (int ni = 0; ni < 4; ++ni)
            acc[mi][ni] = __builtin_amdgcn_mfma_f32_16x16x32_bf16(
                bg[ni], af[mi], acc[mi][ni], 0, 0, 0);
      }
    }
  }

  if (!vblk) {
    const bool isq = (n0 < 256);
#pragma unroll
    for (int mi = 0; mi < 4; ++mi) {
      int mbase = m0 + wm * 64 + mi * 16 + lhi * 4;
#pragma unroll
      for (int ni = 0; ni < 4; ++ni) {
        int n = n0 + wn * 64 + ni * 16 + l16;
        int s = n >> 8, hh = (n >> 6) & 3, d = n & 63;
        float bv = bias[n];
#pragma unroll
        for (int r = 0; r < 4; ++r) {
          int m = mbase + r;
          int b = m >> 10, rw = m & 1023;
          float v = acc[mi][ni][r] + bv;
          if (isq) v *= 0.125f;
          qkp[(size_t)s * 4194304 + (((size_t)(b * 4 + hh)) * 1024 + rw) * 64 + d] = f2bf(v);
        }
      }
    }
  } else {
#pragma unroll
    for (int mi = 0; mi < 4; ++mi) {
#pragma unroll
      for (int ni = 0; ni < 4; ++ni) {
#pragma unroll
        for (int r = 0; r < 4; ++r) {
          int n = n0 + wn * 64 + ni * 16 + lhi * 4 + r;   // 512..767
          int hh = (n >> 6) & 3, d = n & 63;
          int m = m0 + wm * 64 + mi * 16 + l16;
          int b = m >> 10, rw = m & 1023;
          float v = acc[mi][ni][r] + bias[n];
          vtp[(((size_t)(b * 4 + hh)) * 64 + d) * 1024 + rw] = f2bf(v);
        }
      }
    }
  }
}

// ---------------- mean over rows of v^T[bh][d][row] -> bf16[bh][d] ----------------
__global__ __launch_bounds__(256)
void vmean_kernel(const short* __restrict__ vt, short* __restrict__ vmb) {
  __shared__ float part[64][4];
  int bh = blockIdx.x;
  int d = threadIdx.x >> 2, seg = threadIdx.x & 3;
  const short* p = vt + (size_t)bh * 65536 + (size_t)d * 1024 + seg * 256;
  float s = 0.f;
  for (int i = 0; i < 256; i += 8) {
    bf16x8 v = *(const bf16x8*)(p + i);
#pragma unroll
    for (int j = 0; j < 8; ++j) s += bf2f(v[j]);
  }
  part[d][seg] = s;
  __syncthreads();
  if (threadIdx.x < 64) {
    int dd = threadIdx.x;
    float tot = part[dd][0] + part[dd][1] + part[dd][2] + part[dd][3];
    vmb[bh * 64 + dd] = f2bf(tot * (1.f / 1024.f));
  }
}

// ---------------- MFMA flash attention, split-K over blockIdx.z (r10) ------------
__global__ __launch_bounds__(256)
void fattn_mfma(const short* __restrict__ qpk, const short* __restrict__ kpk,
                const short* __restrict__ vt, const float* __restrict__ Kmat,
                const int* __restrict__ n1, const int* __restrict__ n2,
                const short* __restrict__ vmb, short* __restrict__ o,
                float* __restrict__ pO, float* __restrict__ pL,
                int tiles_per_split) {
  int bh = blockIdx.y, b = bh >> 2, hh = bh & 3;
  int qt = blockIdx.x;
  int row0 = qt * 64;
  int sp = blockIdx.z;
  int nc = n1[b] * n2[b];
  int t = threadIdx.x;
  __shared__ short vms[64];
  if (t < 64) vms[t] = vmb[bh * 64 + t];
  __syncthreads();
  if (row0 >= nc) {
    // fully-masked rows: scores identical in fp32 -> uniform softmax -> mean(v)
    if (sp == 0) {
      for (int idx = t; idx < 4096; idx += 256) {
        int r = idx >> 6, d = idx & 63;
        o[((size_t)(b * 1024 + row0 + r)) * 256 + hh * 64 + d] = vms[d];
      }
    }
    return;
  }
  int ntiles = (nc + 63) >> 6;
  int nsp = (ntiles + tiles_per_split - 1) / tiles_per_split;
  int jt0 = sp * tiles_per_split;
  if (jt0 >= ntiles) return;
  int jstart = jt0 * 64;
  int jend = min(jstart + tiles_per_split * 64, nc);
  const bool final_out = (nsp == 1);

  __shared__ __align__(16) short Ks[2][64 * 64];
  __shared__ __align__(16) short Vs[2][64 * 64];
  __shared__ __align__(16) short Ps[64 * 64];
  int w = t >> 6, lane = t & 63, l16 = lane & 15, lhi = lane >> 4;

  constexpr float LOG2E = 1.4426950408889634f;
  constexpr float MREF = 12.0f;  // fixed softmax reference

  // Q fragments (q pre-scaled by 0.125 at QKV epilogue)
  const short* qb = qpk + (size_t)bh * 65536 + (size_t)(row0 + w * 16 + l16) * 64;
  bf16x8 qf0 = *(const bf16x8*)(qb + lhi * 8);
  bf16x8 qf1 = *(const bf16x8*)(qb + 32 + lhi * 8);

  f32x4 accO[4] = {};
  float lsum[4] = {};
  const float* Kb = Kmat + (size_t)b * 1048576 + (size_t)(row0 + w * 16) * 1024;

  f32x4 kvp[4];

  // ---- prologue: stage first tile, prefetch its bias ----
#pragma unroll
  for (int i = 0; i < 2; ++i) {
    int cc = i * 256 + t;
    int r = cc >> 3, sl = cc & 7, ssl = sl ^ (r & 7);
    GLDS(kpk + (size_t)bh * 65536 + (size_t)(jstart + r) * 64 + ssl * 8, &Ks[0][cc * 8]);
    GLDS(vt + (size_t)bh * 65536 + (size_t)r * 1024 + jstart + ssl * 8, &Vs[0][cc * 8]);
  }
#pragma unroll
  for (int ni = 0; ni < 4; ++ni)
#pragma unroll
    for (int r = 0; r < 4; ++r)
      kvp[ni][r] =
          (Kb[(size_t)(lhi * 4 + r) * 1024 + jstart + ni * 16 + l16] - MREF) * LOG2E;

  int cur = 0;
  for (int j0 = jstart; j0 < jend; j0 += 64, cur ^= 1) {
    asm volatile("s_waitcnt vmcnt(0)" ::: "memory");
    __syncthreads();  // tile j ready; buf[cur^1] free

    f32x4 kvc[4];
#pragma unroll
    for (int i = 0; i < 4; ++i) kvc[i] = kvp[i];
    int jn = j0 + 64;
    if (jn < jend) {
      int nxt = cur ^ 1;
#pragma unroll
      for (int i = 0; i < 2; ++i) {
        int cc = i * 256 + t;
        int r = cc >> 3, sl = cc & 7, ssl = sl ^ (r & 7);
        GLDS(kpk + (size_t)bh * 65536 + (size_t)(jn + r) * 64 + ssl * 8, &Ks[nxt][cc * 8]);
        GLDS(vt + (size_t)bh * 65536 + (size_t)r * 1024 + jn + ssl * 8, &Vs[nxt][cc * 8]);
      }
#pragma unroll
      for (int ni = 0; ni < 4; ++ni)
#pragma unroll
        for (int r = 0; r < 4; ++r)
          kvp[ni][r] =
              (Kb[(size_t)(lhi * 4 + r) * 1024 + jn + ni * 16 + l16] - MREF) * LOG2E;
    }

    // QK^T: S[q=16 rows of wave][64 cols]
    f32x4 accS[4] = {};
#pragma unroll
    for (int ks = 0; ks < 2; ++ks) {
#pragma unroll
      for (int ni = 0; ni < 4; ++ni) {
        int row = ni * 16 + l16;
        bf16x8 kf = *(const bf16x8*)&Ks[cur][row * 64 + (((ks * 4 + lhi) ^ (row & 7)) << 3)];
        accS[ni] = __builtin_amdgcn_mfma_f32_16x16x32_bf16(
            ks ? qf1 : qf0, kf, accS[ni], 0, 0, 0);
      }
    }

    // fixed-reference softmax: e = exp2(S*log2e + (K-M)*log2e), masked cols -> 0
#pragma unroll
    for (int ni = 0; ni < 4; ++ni) {
      bool valid = (j0 + ni * 16 + l16) < nc;
#pragma unroll
      for (int r = 0; r < 4; ++r) {
        float e = __builtin_amdgcn_exp2f(fmaf(accS[ni][r], LOG2E, kvc[ni][r]));
        e = valid ? e : 0.f;
        lsum[r] += e;
        int prow = w * 16 + lhi * 4 + r;
        int col = ni * 16 + l16;
        Ps[prow * 64 + ((((col >> 3) ^ (prow & 7)) << 3) | (col & 7))] = f2bf(e);
      }
    }

    // PV: O[16 q][64 d] += P[16 q][64 k] @ Vt[d][k]^T  (Ps rows wave-private)
#pragma unroll
    for (int ks = 0; ks < 2; ++ks) {
      int prow = w * 16 + l16;
      bf16x8 pf = *(const bf16x8*)&Ps[prow * 64 + (((ks * 4 + lhi) ^ (prow & 7)) << 3)];
#pragma unroll
      for (int ni = 0; ni < 4; ++ni) {
        int vrow = ni * 16 + l16;
        bf16x8 vf = *(const bf16x8*)&Vs[cur][vrow * 64 + (((ks * 4 + lhi) ^ (vrow & 7)) << 3)];
        accO[ni] = __builtin_amdgcn_mfma_f32_16x16x32_bf16(pf, vf, accO[ni], 0, 0, 0);
      }
    }
  }

  // one-time denominator reduce over the 16-lane col group
#pragma unroll
  for (int r = 0; r < 4; ++r) {
    lsum[r] += __shfl_xor(lsum[r], 1);
    lsum[r] += __shfl_xor(lsum[r], 2);
    lsum[r] += __shfl_xor(lsum[r], 4);
    lsum[r] += __shfl_xor(lsum[r], 8);
  }

  if (final_out) {
    // epilogue: direct output
#pragma unroll
    for (int ni = 0; ni < 4; ++ni) {
#pragma unroll
      for (int r = 0; r < 4; ++r) {
        int row = row0 + w * 16 + lhi * 4 + r;
        int d = ni * 16 + l16;
        short ov;
        if (row < nc) ov = f2bf(accO[ni][r] * (1.f / lsum[r]));
        else ov = vms[d];
        o[((size_t)(b * 1024 + row)) * 256 + hh * 64 + d] = ov;
      }
    }
  } else {
    // write fp32 partials; combine kernel sums over splits (fixed order)
    float* po = pO + (((size_t)sp * 64 + bh) * 16 + qt) * 4096;
#pragma unroll
    for (int ni = 0; ni < 4; ++ni)
#pragma unroll
      for (int r = 0; r < 4; ++r)
        po[(w * 16 + lhi * 4 + r) * 64 + ni * 16 + l16] = accO[ni][r];
    if (l16 == 0) {
      float* pl = pL + (((size_t)sp * 64 + bh) * 16 + qt) * 64;
#pragma unroll
      for (int r = 0; r < 4; ++r) pl[w * 16 + lhi * 4 + r] = lsum[r];
    }
    // mean-fill rows >= nc handled once (split covering jstart==0)
    if (sp == 0) {
      for (int idx = t; idx < 4096; idx += 256) {
        int r = idx >> 6, d = idx & 63;
        int row = row0 + r;
        if (row >= nc)
          o[((size_t)(b * 1024 + row)) * 256 + hh * 64 + d] = vms[d];
      }
    }
  }
}

// ---------------- combine split-K partials -> bf16 output ----------------
__global__ __launch_bounds__(256)
void fattn_combine(const float* __restrict__ pO, const float* __restrict__ pL,
                   const int* __restrict__ n1, const int* __restrict__ n2,
                   short* __restrict__ o, int tiles_per_split) {
  int bh = blockIdx.y, b = bh >> 2, hh = bh & 3;
  int qt = blockIdx.x;
  int row0 = qt * 64;
  int nc = n1[b] * n2[b];
  if (row0 >= nc) return;
  int ntiles = (nc + 63) >> 6;
  int nsp = (ntiles + tiles_per_split - 1) / tiles_per_split;
  if (nsp < 2) return;  // fattn wrote final output

  int t = threadIdx.x;
  int q = t >> 2, ds = (t & 3) * 16;
  int row = row0 + q;
  if (row >= nc) return;

  const size_t spstrideO = (size_t)64 * 16 * 4096;
  const size_t spstrideL = (size_t)64 * 16 * 64;
  const float* baseO = pO + ((size_t)bh * 16 + qt) * 4096 + q * 64 + ds;
  const float* baseL = pL + ((size_t)bh * 16 + qt) * 64 + q;

  f32x4 s[4] = {};
  float L = 0.f;
  for (int sp = 0; sp < nsp; ++sp) {
    const float* p = baseO + sp * spstrideO;
#pragma unroll
    for (int i = 0; i < 4; ++i) s[i] += *(const f32x4*)(p + i * 4);
    L += baseL[sp * spstrideL];
  }
  float rl = 1.f / L;
  short* op = o + ((size_t)(b * 1024 + row)) * 256 + hh * 64 + ds;
#pragma unroll
  for (int i = 0; i < 4; ++i) {
    short4 ov;
    ov.x = f2bf(s[i][0] * rl);
    ov.y = f2bf(s[i][1] * rl);
    ov.z = f2bf(s[i][2] * rl);
    ov.w = f2bf(s[i][3] * rl);
    *(short4*)(op + i * 4) = ov;
  }
}

// ---------------- fused proj GEMM + residual + LayerNorm2 ----------------
__global__ __launch_bounds__(256)
void proj_ln_mfma(const short* __restrict__ A, const short* __restrict__ Bw,
                  const float* __restrict__ bias, const float* __restrict__ resid,
                  const float* __restrict__ g2, const float* __restrict__ b2,
                  float* __restrict__ Cf, short* __restrict__ h2) {
  __shared__ __align__(16) short As[2][64 * 64];    // 16 KB
  __shared__ __align__(16) short Bs[2][256 * 64];   // 64 KB
  int t = threadIdx.x;
  int w = t >> 6, lane = t & 63;
  int l16 = lane & 15, lhi = lane >> 4;
  int m0 = blockIdx.x * 64;
  constexpr int Kd = 256;
  f32x4 acc[4][4] = {};

  // prologue: stage tile 0
#pragma unroll
  for (int i = 0; i < 2; ++i) {
    int cc = i * 256 + t;
    int r = cc >> 3, sl = cc & 7, ssl = sl ^ (r & 7);
    GLDS(A + (size_t)(m0 + r) * Kd + ssl * 8, &As[0][cc * 8]);
  }
#pragma unroll
  for (int i = 0; i < 8; ++i) {
    int cc = i * 256 + t;
    int r = cc >> 3, sl = cc & 7, ssl = sl ^ (r & 7);
    GLDS(Bw + (size_t)r * Kd + ssl * 8, &Bs[0][cc * 8]);
  }

  int cur = 0;
  for (int k0 = 0; k0 < Kd; k0 += 64, cur ^= 1) {
    asm volatile("s_waitcnt vmcnt(0)" ::: "memory");
    __syncthreads();
    int kn = k0 + 64;
    if (kn < Kd) {
      int nxt = cur ^ 1;
#pragma unroll
      for (int i = 0; i < 2; ++i) {
        int cc = i * 256 + t;
        int r = cc >> 3, sl = cc & 7, ssl = sl ^ (r & 7);
        GLDS(A + (size_t)(m0 + r) * Kd + kn + ssl * 8, &As[nxt][cc * 8]);
      }
#pragma unroll
      for (int i = 0; i < 8; ++i) {
        int cc = i * 256 + t;
        int r = cc >> 3, sl = cc & 7, ssl = sl ^ (r & 7);
        GLDS(Bw + (size_t)r * Kd + kn + ssl * 8, &Bs[nxt][cc * 8]);
      }
    }
#pragma unroll
    for (int ks = 0; ks < 2; ++ks) {
      bf16x8 af[4], bg[4];
#pragma unroll
      for (int mi = 0; mi < 4; ++mi) {
        int row = mi * 16 + l16;
        af[mi] = *(const bf16x8*)&As[cur][row * 64 + ((ks * 32 + lhi * 8) ^ ((row & 7) << 3))];
      }
#pragma unroll
      for (int ni = 0; ni < 4; ++ni) {
        int row = w * 64 + ni * 16 + l16;
        bg[ni] = *(const bf16x8*)&Bs[cur][row * 64 + ((ks * 32 + lhi * 8) ^ ((row & 7) << 3))];
      }
#pragma unroll
      for (int mi = 0; mi < 4; ++mi)
#pragma unroll
        for (int ni = 0; ni < 4; ++ni)
          acc[mi][ni] = __builtin_amdgcn_mfma_f32_16x16x32_bf16(
              af[mi], bg[ni], acc[mi][ni], 0, 0, 0);
    }
  }

  // epilogue: v = acc + bias + resid; write fp32 out; keep v in acc
  float bv[4], gl[4], bl[4];
#pragma unroll
  for (int ni = 0; ni < 4; ++ni) {
    int n = w * 64 + ni * 16 + l16;
    bv[ni] = bias[n];
    gl[ni] = g2[n];
    bl[ni] = b2[n];
  }
#pragma unroll
  for (int mi = 0; mi < 4; ++mi)
#pragma unroll
    for (int ni = 0; ni < 4; ++ni) {
      int n = w * 64 + ni * 16 + l16;
#pragma unroll
      for (int r = 0; r < 4; ++r) {
        int m = m0 + mi * 16 + lhi * 4 + r;
        size_t idx = (size_t)m * 256 + n;
        float v = acc[mi][ni][r] + bv[ni] + resid[idx];
        acc[mi][ni][r] = v;
        Cf[idx] = v;
      }
    }

  // per-row stats: thread-local over ni, shuffle over l16, LDS across waves
  float s[4][4], qq[4][4];
#pragma unroll
  for (int mi = 0; mi < 4; ++mi)
#pragma unroll
    for (int r = 0; r < 4; ++r) {
      float a0 = acc[mi][0][r], a1 = acc[mi][1][r];
      float a2 = acc[mi][2][r], a3 = acc[mi][3][r];
      s[mi][r] = a0 + a1 + a2 + a3;
      qq[mi][r] = a0 * a0 + a1 * a1 + a2 * a2 + a3 * a3;
    }
#pragma unroll
  for (int off = 1; off <= 8; off <<= 1)
#pragma unroll
    for (int mi = 0; mi < 4; ++mi)
#pragma unroll
      for (int r = 0; r < 4; ++r) {
        s[mi][r] += __shfl_xor(s[mi][r], off);
        qq[mi][r] += __shfl_xor(qq[mi][r], off);
      }

  __syncthreads();  // all waves done reading As/Bs; safe to alias As
  float* partS = (float*)&As[0][0];   // [4 waves][64 rows]
  float* partQ = partS + 256;
  if (l16 == 0) {
#pragma unroll
    for (int mi = 0; mi < 4; ++mi)
#pragma unroll
      for (int r = 0; r < 4; ++r) {
        int row = mi * 16 + lhi * 4 + r;
        partS[w * 64 + row] = s[mi][r];
        partQ[w * 64 + row] = qq[mi][r];
      }
  }
  __syncthreads();

#pragma unroll
  for (int mi = 0; mi < 4; ++mi)
#pragma unroll
    for (int r = 0; r < 4; ++r) {
      int row = mi * 16 + lhi * 4 + r;
      float S = partS[row] + partS[64 + row] + partS[128 + row] + partS[192 + row];
      float Q = partQ[row] + partQ[64 + row] + partQ[128 + row] + partQ[192 + row];
      float mean = S * (1.f / 256.f);
      float var = Q * (1.f / 256.f) - mean * mean;
      float inv = rsqrtf(var + EPSV);
      int m = m0 + row;
#pragma unroll
      for (int ni = 0; ni < 4; ++ni) {
        int n = w * 64 + ni * 16 + l16;
        h2[(size_t)m * 256 + n] =
            f2bf((acc[mi][ni][r] - mean) * inv * gl[ni] + bl[ni]);
      }
    }
}

// ---------------- bf16 MFMA GEMM 128x128, 2-phase pipelined ----------------
template <bool GELU, bool RES, bool OUTF, bool OUTB>
__global__ __launch_bounds__(256)
void gemm_mfma(const short* __restrict__ A, const short* __restrict__ Bw,
               const float* __restrict__ bias, const float* __restrict__ resid,
               float* __restrict__ Cf, short* __restrict__ Cb,
               int M, int Nd, int Kd) {
  __shared__ __align__(16) short As[2][128 * 64];
  __shared__ __align__(16) short Bs[2][128 * 64];
  int t = threadIdx.x;
  int w = t >> 6, lane = t & 63;
  int wm = w >> 1, wn = w & 1;
  int l16 = lane & 15, lhi = lane >> 4;
  int m0 = blockIdx.y * 128, n0 = blockIdx.x * 128;
  f32x4 acc[4][4] = {};

  // prologue: stage tile 0 into buf 0
#pragma unroll
  for (int i = 0; i < 4; ++i) {
    int cc = i * 256 + t;
    int r = cc >> 3, sl = cc & 7, ssl = sl ^ (r & 7);
    GLDS(A + (size_t)(m0 + r) * Kd + ssl * 8, &As[0][cc * 8]);
    GLDS(Bw + (size_t)(n0 + r) * Kd + ssl * 8, &Bs[0][cc * 8]);
  }

  int cur = 0;
  for (int k0 = 0; k0 < Kd; k0 += 64, cur ^= 1) {
    asm volatile("s_waitcnt vmcnt(0)" ::: "memory");
    __syncthreads();  // tile k ready; buf[cur^1] free
    int kn = k0 + 64;
    if (kn < Kd) {
      int nxt = cur ^ 1;
#pragma unroll
      for (int i = 0; i < 4; ++i) {
        int cc = i * 256 + t;
        int r = cc >> 3, sl = cc & 7, ssl = sl ^ (r & 7);
        GLDS(A + (size_t)(m0 + r) * Kd + kn + ssl * 8, &As[nxt][cc * 8]);
        GLDS(Bw + (size_t)(n0 + r) * Kd + kn + ssl * 8, &Bs[nxt][cc * 8]);
      }
    }
#pragma unroll
    for (int ks = 0; ks < 2; ++ks) {
      bf16x8 af[4], bg[4];
#pragma unroll
      for (int mi = 0; mi < 4; ++mi) {
        int row = wm * 64 + mi * 16 + l16;
        af[mi] = *(const bf16x8*)&As[cur][row * 64 + ((ks * 32 + lhi * 8) ^ ((row & 7) << 3))];
      }
#pragma unroll
      for (int ni = 0; ni < 4; ++ni) {
        int row = wn * 64 + ni * 16 + l16;
        bg[ni] = *(const bf16x8*)&Bs[cur][row * 64 + ((ks * 32 + lhi * 8) ^ ((row & 7) << 3))];
      }
#pragma unroll
      for (int mi = 0; mi < 4; ++mi)
#pragma unroll
        for (int ni = 0; ni < 4; ++ni)
          acc[mi][ni] = __builtin_amdgcn_mfma_f32_16x16x32_bf16(
              af[mi], bg[ni], acc[mi][ni], 0, 0, 0);
    }
  }
#pragma unroll
  for (int mi = 0; mi < 4; ++mi) {
    int rbase = m0 + wm * 64 + mi * 16 + lhi * 4;
#pragma unroll
    for (int ni = 0; ni < 4; ++ni) {
      int n = n0 + wn * 64 + ni * 16 + l16;
      float bv = bias[n];
#pragma unroll
      for (int r = 0; r < 4; ++r) {
        int m = rbase + r;
        float v = acc[mi][ni][r] + bv;
        if (GELU) v = gelu_fast(v);
        size_t idx = (size_t)m * Nd + n;
        if (RES) v += resid[idx];
        if (OUTF) Cf[idx] = v;
        if (OUTB) Cb[idx] = f2bf(v);
      }
    }
  }
}

// ---------------- bf16 MFMA GEMM 64x128, 2-phase pipelined ----------------
template <bool GELU, bool RES, bool OUTF, bool OUTB>
__global__ __launch_bounds__(256)
void gemm64_mfma(const short* __restrict__ A, const short* __restrict__ Bw,
                 const float* __restrict__ bias, const float* __restrict__ resid,
                 float* __restrict__ Cf, short* __restrict__ Cb,
                 int M, int Nd, int Kd) {
  __shared__ __align__(16) short As[2][64 * 64];
  __shared__ __align__(16) short Bs[2][128 * 64];
  int t = threadIdx.x;
  int w = t >> 6, lane = t & 63;
  int l16 = lane & 15, lhi = lane >> 4;
  int m0 = blockIdx.y * 64, n0 = blockIdx.x * 128;
  f32x4 acc[4][2] = {};

  // prologue: stage tile 0 into buf 0
#pragma unroll
  for (int i = 0; i < 2; ++i) {
    int cc = i * 256 + t;
    int r = cc >> 3, sl = cc & 7, ssl = sl ^ (r & 7);
    GLDS(A + (size_t)(m0 + r) * Kd + ssl * 8, &As[0][cc * 8]);
  }
#pragma unroll
  for (int i = 0; i < 4; ++i) {
    int cc = i * 256 + t;
    int r = cc >> 3, sl = cc & 7, ssl = sl ^ (r & 7);
    GLDS(Bw + (size_t)(n0 + r) * Kd + ssl * 8, &Bs[0][cc * 8]);
  }

  int cur = 0;
  for (int k0 = 0; k0 < Kd; k0 += 64, cur ^= 1) {
    asm volatile("s_waitcnt vmcnt(0)" ::: "memory");
    __syncthreads();  // tile k ready; buf[cur^1] free
    int kn = k0 + 64;
    if (kn < Kd) {
      int nxt = cur ^ 1;
#pragma unroll
      for (int i = 0; i < 2; ++i) {
        int cc = i * 256 + t;
        int r = cc >> 3, sl = cc & 7, ssl = sl ^ (r & 7);
        GLDS(A + (size_t)(m0 + r) * Kd + kn + ssl * 8, &As[nxt][cc * 8]);
      }
#pragma unroll
      for (int i = 0; i < 4; ++i) {
        int cc = i * 256 + t;
        int r = cc >> 3, sl = cc & 7, ssl = sl ^ (r & 7);
        GLDS(Bw + (size_t)(n0 + r) * Kd + kn + ssl * 8, &Bs[nxt][cc * 8]);
      }
    }
#pragma unroll
    for (int ks = 0; ks < 2; ++ks) {
      bf16x8 af[4], bg[2];
#pragma unroll
      for (int mi = 0; mi < 4; ++mi) {
        int row = mi * 16 + l16;
        af[mi] = *(const bf16x8*)&As[cur][row * 64 + ((ks * 32 + lhi * 8) ^ ((row & 7) << 3))];
      }
#pragma unroll
      for (int ni = 0; ni < 2; ++ni) {
        int row = w * 32 + ni * 16 + l16;
        bg[ni] = *(const bf16x8*)&Bs[cur][row * 64 + ((ks * 32 + lhi * 8) ^ ((row & 7) << 3))];
      }
#pragma unroll
      for (int mi = 0; mi < 4; ++mi)
#pragma unroll
        for (int ni = 0; ni < 2; ++ni)
          acc[mi][ni] = __builtin_amdgcn_mfma_f32_16x16x32_bf16(
              af[mi], bg[ni], acc[mi][ni], 0, 0, 0);
    }
  }
#pragma unroll
  for (int mi = 0; mi < 4; ++mi) {
    int rbase = m0 + mi * 16 + lhi * 4;
#pragma unroll
    for (int ni = 0; ni < 2; ++ni) {
      int n = n0 + w * 32 + ni * 16 + l16;
      float bv = bias[n];
#pragma unroll
      for (int r = 0; r < 4; ++r) {
        int m = rbase + r;
        float v = acc[mi][ni][r] + bv;
        if (GELU) v = gelu_fast(v);
        size_t idx = (size_t)m * Nd + n;
        if (RES) v += resid[idx];
        if (OUTF) Cf[idx] = v;
        if (OUTB) Cb[idx] = f2bf(v);
      }
    }
  }
}

extern "C" void kernel_launch(void* const* d_in, const int* in_sizes, int n_in,
                              void* d_out, int out_size, void* d_ws, size_t ws_size,
                              hipStream_t stream) {
  const float* x      = (const float*)d_in[0];
  const float* Kmat   = (const float*)d_in[1];
  const int*   n1     = (const int*)d_in[2];
  const int*   n2     = (const int*)d_in[3];
  const float* qkv_w  = (const float*)d_in[4];
  const float* qkv_b  = (const float*)d_in[5];
  const float* proj_w = (const float*)d_in[6];
  const float* proj_b = (const float*)d_in[7];
  const float* ln1_g  = (const float*)d_in[8];
  const float* ln1_b  = (const float*)d_in[9];
  const float* ln2_g  = (const float*)d_in[10];
  const float* ln2_b  = (const float*)d_in[11];
  const float* fc1_w  = (const float*)d_in[12];
  const float* fc1_b  = (const float*)d_in[13];
  const float* fc2_w  = (const float*)d_in[14];
  const float* fc2_b  = (const float*)d_in[15];
  float* out = (float*)d_out;

  char* ws = (char*)d_ws;
  constexpr size_t MB = 1024 * 1024;
  // layout:
  //  [0,8): hb bf16 (LN1 out -> obuf attn out)
  //  [8,24): qkp bf16 (qpk at 8, kpk at 16); [24,32): vt bf16 [bh][d][row]
  //  [8,40): m1 bf16 (fc1 out; overlays qkp/vt AFTER attention)
  //  [40]: vmb ; [41..45): bf16 weights
  //  [48,116): split-K partial O fp32 (dead after combine) -> hb2 (LN2 out)
  //  [116,117): partial L fp32
  short* hb    = (short*)ws;
  short* qkp   = (short*)(ws + 8 * MB);
  short* vtp   = (short*)(ws + 24 * MB);
  short* m1    = (short*)(ws + 8 * MB);
  short* vmb   = (short*)(ws + 40 * MB);
  short* wqkv  = (short*)(ws + 41 * MB);
  short* wproj = (short*)(ws + 42 * MB);
  short* wfc1  = (short*)(ws + 43 * MB);
  short* wfc2  = (short*)(ws + 44 * MB);
  float* pO    = (float*)(ws + 48 * MB);
  float* pL    = (float*)(ws + 116 * MB);
  short* hb2   = (short*)(ws + 48 * MB);  // reuses pO region (dead by proj time)
  short* obuf  = hb;
  short* qpk   = qkp;
  short* kpk   = qkp + 4194304;

  const bool split = ws_size >= (size_t)118 * MB;

  // 0+1) weights -> bf16 AND h = LN1(x) -> bf16 (single launch)
  prep_kernel<<<dim3(768 + Mrows / 4), 256, 0, stream>>>(
      qkv_w, wqkv, proj_w, wproj, fc1_w, wfc1, fc2_w, wfc2,
      x, ln1_g, ln1_b, hb);
  // 2) qkv GEMM -> packed bf16 q (x0.125), k [bh][row][d]; v^T [bh][d][row]
  qkv_mfma<<<dim3(6, 128), 256, 0, stream>>>(hb, wqkv, qkv_b, qkp, vtp);
  // 3) per-(b,h) mean of v
  vmean_kernel<<<dim3(Bc * Hh), 256, 0, stream>>>(vtp, vmb);
  // 4) MFMA flash attention -> obuf bf16 [B,N,C] (split-K caps serial chain at 4)
  if (split) {
    fattn_mfma<<<dim3(Nn / 64, Bc * Hh, 4), 256, 0, stream>>>(
        qpk, kpk, vtp, Kmat, n1, n2, vmb, obuf, pO, pL, 4);
    fattn_combine<<<dim3(Nn / 64, Bc * Hh), 256, 0, stream>>>(
        pO, pL, n1, n2, obuf, 4);
  } else {
    fattn_mfma<<<dim3(Nn / 64, Bc * Hh, 1), 256, 0, stream>>>(
        qpk, kpk, vtp, Kmat, n1, n2, vmb, obuf, pO, pL, 16);
  }
  // 5+6) out = x + obuf @ proj_w^T + proj_b (fp32) AND hb2 = LN2(out) bf16, fused
  proj_ln_mfma<<<dim3(256), 256, 0, stream>>>(
      obuf, wproj, proj_b, x, ln2_g, ln2_b, out, hb2);
  // 7) m1 = GELU(hb2 @ fc1_w^T + fc1_b) -> bf16
  gemm_mfma<true, false, false, true><<<dim3(8, 128), 256, 0, stream>>>(
      hb2, wfc1, fc1_b, nullptr, nullptr, m1, Mrows, 1024, 256);
  // 8) out = out + m1 @ fc2_w^T + fc2_b (in-place residual) [64-row tiles]
  gemm64_mfma<false, true, true, false><<<dim3(2, 256), 256, 0, stream>>>(
      m1, wfc2, fc2_b, out, out, nullptr, Mrows, 256, 1024);
}

// Round 13
// 127.954 us; speedup vs baseline: 1.0662x; 1.0046x over previous
//
#include <hip/hip_runtime.h>
#include <math.h>
#include <stdint.h>

// Shapes (fixed by the problem)
constexpr int Bc = 16, Nn = 1024, Cc = 256, Hh = 4;
constexpr int Mrows = Bc * Nn;          // 16384
constexpr float EPSV = 1e-5f;

typedef __attribute__((ext_vector_type(4))) float f32x4;
typedef __attribute__((ext_vector_type(8))) short bf16x8;

__device__ inline float wave_reduce_sum(float v) {
#pragma unroll
  for (int m = 32; m >= 1; m >>= 1) v += __shfl_xor(v, m);
  return v;
}

__device__ inline short f2bf(float f) {
  uint32_t u = __builtin_bit_cast(uint32_t, f);
  u = (u + 0x7fffu + ((u >> 16) & 1u)) >> 16;  // RNE
  return (short)u;
}
__device__ inline float bf2f(short s) {
  uint32_t u = ((uint32_t)(uint16_t)s) << 16;
  return __builtin_bit_cast(float, u);
}

// branch-free tanh-form GELU: x * sigmoid(2u), u = sqrt(2/pi)*(x + 0.044715 x^3)
__device__ inline float gelu_fast(float x) {
  float x2 = x * x;
  float u = x * (0.7978845608028654f + 0.0356774081f * x2);
  float e = __builtin_amdgcn_exp2f(u * 2.8853900817779268f);  // exp(2u)
  return x * (1.f - __builtin_amdgcn_rcpf(e + 1.f));
}

#define GLDS(gptr, lptr)                                             \
  __builtin_amdgcn_global_load_lds(                                  \
      (const __attribute__((address_space(1))) void*)(gptr),         \
      (__attribute__((address_space(3))) void*)(lptr), 16, 0, 0)

// ------- prep: weight fp32->bf16 (blocks 0..767) + LN1 (blocks 768..4863) -------
__global__ __launch_bounds__(256)
void prep_kernel(const float* __restrict__ s0, short* __restrict__ d0,   // 192 blk
                 const float* __restrict__ s1, short* __restrict__ d1,   //  64 blk
                 const float* __restrict__ s2, short* __restrict__ d2,   // 256 blk
                 const float* __restrict__ s3, short* __restrict__ d3,   // 256 blk
                 const float* __restrict__ x, const float* __restrict__ g,
                 const float* __restrict__ b, short* __restrict__ h) {
  int bid = blockIdx.x;
  if (bid < 768) {
    const float* s;
    short* d;
    int base;
    if (bid < 192)      { s = s0; d = d0; base = bid; }
    else if (bid < 256) { s = s1; d = d1; base = bid - 192; }
    else if (bid < 512) { s = s2; d = d2; base = bid - 256; }
    else                { s = s3; d = d3; base = bid - 512; }
    int i = (base * 256 + threadIdx.x) * 4;
    float4 v = *(const float4*)(s + i);
    short4 o;
    o.x = f2bf(v.x); o.y = f2bf(v.y); o.z = f2bf(v.z); o.w = f2bf(v.w);
    *(short4*)(d + i) = o;
  } else {
    int row = (bid - 768) * 4 + (threadIdx.x >> 6);
    int lane = threadIdx.x & 63;
    const float4* xr = (const float4*)(x + (size_t)row * Cc);
    float4 v = xr[lane];
    float s = v.x + v.y + v.z + v.w;
    float sq = v.x * v.x + v.y * v.y + v.z * v.z + v.w * v.w;
    s = wave_reduce_sum(s);
    sq = wave_reduce_sum(sq);
    float mean = s * (1.f / Cc);
    float var = sq * (1.f / Cc) - mean * mean;
    float inv = rsqrtf(var + EPSV);
    float4 gg = ((const float4*)g)[lane];
    float4 bb = ((const float4*)b)[lane];
    short4 o;
    o.x = f2bf((v.x - mean) * inv * gg.x + bb.x);
    o.y = f2bf((v.y - mean) * inv * gg.y + bb.y);
    o.z = f2bf((v.z - mean) * inv * gg.z + bb.z);
    o.w = f2bf((v.w - mean) * inv * gg.w + bb.w);
    *(short4*)(h + (size_t)row * Cc + lane * 4) = o;
  }
}

// ---------------- QKV GEMM, 2-phase pipelined, packed scatter ----------------
__global__ __launch_bounds__(256)
void qkv_mfma(const short* __restrict__ A, const short* __restrict__ Bw,
              const float* __restrict__ bias, short* __restrict__ qkp,
              short* __restrict__ vtp) {
  __shared__ __align__(16) short As[2][128 * 64];
  __shared__ __align__(16) short Bs[2][128 * 64];
  int t = threadIdx.x;
  int w = t >> 6, lane = t & 63;
  int wm = w >> 1, wn = w & 1;
  int l16 = lane & 15, lhi = lane >> 4;
  int m0 = blockIdx.y * 128, n0 = blockIdx.x * 128;
  const bool vblk = (n0 >= 512);
  f32x4 acc[4][4] = {};

  // prologue: stage tile 0 into buf 0
#pragma unroll
  for (int i = 0; i < 4; ++i) {
    int cc = i * 256 + t;
    int r = cc >> 3, sl = cc & 7, ssl = sl ^ (r & 7);
    GLDS(A + (size_t)(m0 + r) * 256 + ssl * 8, &As[0][cc * 8]);
    GLDS(Bw + (size_t)(n0 + r) * 256 + ssl * 8, &Bs[0][cc * 8]);
  }

  int cur = 0;
  for (int k0 = 0; k0 < 256; k0 += 64, cur ^= 1) {
    asm volatile("s_waitcnt vmcnt(0)" ::: "memory");
    __syncthreads();  // tile k ready; buf[cur^1] free (prev compute done)
    int kn = k0 + 64;
    if (kn < 256) {
      int nxt = cur ^ 1;
#pragma unroll
      for (int i = 0; i < 4; ++i) {
        int cc = i * 256 + t;
        int r = cc >> 3, sl = cc & 7, ssl = sl ^ (r & 7);
        GLDS(A + (size_t)(m0 + r) * 256 + kn + ssl * 8, &As[nxt][cc * 8]);
        GLDS(Bw + (size_t)(n0 + r) * 256 + kn + ssl * 8, &Bs[nxt][cc * 8]);
      }
    }
#pragma unroll
    for (int ks = 0; ks < 2; ++ks) {
      bf16x8 af[4], bg[4];
#pragma unroll
      for (int mi = 0; mi < 4; ++mi) {
        int row = wm * 64 + mi * 16 + l16;
        af[mi] = *(const bf16x8*)&As[cur][row * 64 + ((ks * 32 + lhi * 8) ^ ((row & 7) << 3))];
      }
#pragma unroll
      for (int ni = 0; ni < 4; ++ni) {
        int row = wn * 64 + ni * 16 + l16;
        bg[ni] = *(const bf16x8*)&Bs[cur][row * 64 + ((ks * 32 + lhi * 8) ^ ((row & 7) << 3))];
      }
      if (!vblk) {
#pragma unroll
        for (int mi = 0; mi < 4; ++mi)
#pragma unroll
          for (int ni = 0; ni < 4; ++ni)
            acc[mi][ni] = __builtin_amdgcn_mfma_f32_16x16x32_bf16(
                af[mi], bg[ni], acc[mi][ni], 0, 0, 0);
      } else {
        // swapped: C' = C^T (rows of frag = n, cols = m)
#pragma unroll
        for (int mi = 0; mi < 4; ++mi)
#pragma unroll
          for (int ni = 0; ni < 4; ++ni)
            acc[mi][ni] = __builtin_amdgcn_mfma_f32_16x16x32_bf16(
                bg[ni], af[mi], acc[mi][ni], 0, 0, 0);
      }
    }
  }

  if (!vblk) {
    const bool isq = (n0 < 256);
#pragma unroll
    for (int mi = 0; mi < 4; ++mi) {
      int mbase = m0 + wm * 64 + mi * 16 + lhi * 4;
#pragma unroll
      for (int ni = 0; ni < 4; ++ni) {
        int n = n0 + wn * 64 + ni * 16 + l16;
        int s = n >> 8, hh = (n >> 6) & 3, d = n & 63;
        float bv = bias[n];
#pragma unroll
        for (int r = 0; r < 4; ++r) {
          int m = mbase + r;
          int b = m >> 10, rw = m & 1023;
          float v = acc[mi][ni][r] + bv;
          if (isq) v *= 0.125f;
          qkp[(size_t)s * 4194304 + (((size_t)(b * 4 + hh)) * 1024 + rw) * 64 + d] = f2bf(v);
        }
      }
    }
  } else {
#pragma unroll
    for (int mi = 0; mi < 4; ++mi) {
#pragma unroll
      for (int ni = 0; ni < 4; ++ni) {
#pragma unroll
        for (int r = 0; r < 4; ++r) {
          int n = n0 + wn * 64 + ni * 16 + lhi * 4 + r;   // 512..767
          int hh = (n >> 6) & 3, d = n & 63;
          int m = m0 + wm * 64 + mi * 16 + l16;
          int b = m >> 10, rw = m & 1023;
          float v = acc[mi][ni][r] + bias[n];
          vtp[(((size_t)(b * 4 + hh)) * 64 + d) * 1024 + rw] = f2bf(v);
        }
      }
    }
  }
}

// ---------------- mean over rows of v^T[bh][d][row] -> bf16[bh][d] ----------------
__global__ __launch_bounds__(256)
void vmean_kernel(const short* __restrict__ vt, short* __restrict__ vmb) {
  __shared__ float part[64][4];
  int bh = blockIdx.x;
  int d = threadIdx.x >> 2, seg = threadIdx.x & 3;
  const short* p = vt + (size_t)bh * 65536 + (size_t)d * 1024 + seg * 256;
  float s = 0.f;
  for (int i = 0; i < 256; i += 8) {
    bf16x8 v = *(const bf16x8*)(p + i);
#pragma unroll
    for (int j = 0; j < 8; ++j) s += bf2f(v[j]);
  }
  part[d][seg] = s;
  __syncthreads();
  if (threadIdx.x < 64) {
    int dd = threadIdx.x;
    float tot = part[dd][0] + part[dd][1] + part[dd][2] + part[dd][3];
    vmb[bh * 64 + dd] = f2bf(tot * (1.f / 1024.f));
  }
}

// ---------------- MFMA flash attention, split-K over blockIdx.z ----------------
// r12 structure with prologue trims: no vms LDS stage (vmb read direct from L2,
// removes one barrier from every block); Q-fragment loads hoisted above the
// n1/n2-dependent logic so their VMEM issues overlap the nc load.
__global__ __launch_bounds__(256)
void fattn_mfma(const short* __restrict__ qpk, const short* __restrict__ kpk,
                const short* __restrict__ vt, const float* __restrict__ Kmat,
                const int* __restrict__ n1, const int* __restrict__ n2,
                const short* __restrict__ vmb, short* __restrict__ o,
                float* __restrict__ pO, float* __restrict__ pL,
                int tiles_per_split) {
  int bh = blockIdx.y, b = bh >> 2, hh = bh & 3;
  int qt = blockIdx.x;
  int row0 = qt * 64;
  int sp = blockIdx.z;
  int t = threadIdx.x;
  int w = t >> 6, lane = t & 63, l16 = lane & 15, lhi = lane >> 4;

  // Q fragments hoisted (no nc dependency; q pre-scaled by 0.125 at QKV epilogue)
  const short* qb = qpk + (size_t)bh * 65536 + (size_t)(row0 + w * 16 + l16) * 64;
  bf16x8 qf0 = *(const bf16x8*)(qb + lhi * 8);
  bf16x8 qf1 = *(const bf16x8*)(qb + 32 + lhi * 8);

  int nc = n1[b] * n2[b];
  if (row0 >= nc) {
    // fully-masked rows: scores identical in fp32 -> uniform softmax -> mean(v)
    if (sp == 0) {
      for (int idx = t; idx < 4096; idx += 256) {
        int r = idx >> 6, d = idx & 63;
        o[((size_t)(b * 1024 + row0 + r)) * 256 + hh * 64 + d] = vmb[bh * 64 + d];
      }
    }
    return;
  }
  int ntiles = (nc + 63) >> 6;
  int nsp = (ntiles + tiles_per_split - 1) / tiles_per_split;
  int jt0 = sp * tiles_per_split;
  if (jt0 >= ntiles) return;
  int jstart = jt0 * 64;
  int jend = min(jstart + tiles_per_split * 64, nc);
  const bool final_out = (nsp == 1);

  __shared__ __align__(16) short Ks[2][64 * 64];
  __shared__ __align__(16) short Vs[2][64 * 64];
  __shared__ __align__(16) short Ps[64 * 64];

  constexpr float LOG2E = 1.4426950408889634f;
  constexpr float MREF = 12.0f;  // fixed softmax reference

  f32x4 accO[4] = {};
  float lsum[4] = {};
  const float* Kb = Kmat + (size_t)b * 1048576 + (size_t)(row0 + w * 16) * 1024;

  f32x4 kvp[4];

  // ---- prologue: stage first tile, prefetch its bias ----
#pragma unroll
  for (int i = 0; i < 2; ++i) {
    int cc = i * 256 + t;
    int r = cc >> 3, sl = cc & 7, ssl = sl ^ (r & 7);
    GLDS(kpk + (size_t)bh * 65536 + (size_t)(jstart + r) * 64 + ssl * 8, &Ks[0][cc * 8]);
    GLDS(vt + (size_t)bh * 65536 + (size_t)r * 1024 + jstart + ssl * 8, &Vs[0][cc * 8]);
  }
#pragma unroll
  for (int ni = 0; ni < 4; ++ni)
#pragma unroll
    for (int r = 0; r < 4; ++r)
      kvp[ni][r] =
          (Kb[(size_t)(lhi * 4 + r) * 1024 + jstart + ni * 16 + l16] - MREF) * LOG2E;

  int cur = 0;
  for (int j0 = jstart; j0 < jend; j0 += 64, cur ^= 1) {
    asm volatile("s_waitcnt vmcnt(0)" ::: "memory");
    __syncthreads();  // tile j ready; buf[cur^1] free

    f32x4 kvc[4];
#pragma unroll
    for (int i = 0; i < 4; ++i) kvc[i] = kvp[i];
    int jn = j0 + 64;
    if (jn < jend) {
      int nxt = cur ^ 1;
#pragma unroll
      for (int i = 0; i < 2; ++i) {
        int cc = i * 256 + t;
        int r = cc >> 3, sl = cc & 7, ssl = sl ^ (r & 7);
        GLDS(kpk + (size_t)bh * 65536 + (size_t)(jn + r) * 64 + ssl * 8, &Ks[nxt][cc * 8]);
        GLDS(vt + (size_t)bh * 65536 + (size_t)r * 1024 + jn + ssl * 8, &Vs[nxt][cc * 8]);
      }
#pragma unroll
      for (int ni = 0; ni < 4; ++ni)
#pragma unroll
        for (int r = 0; r < 4; ++r)
          kvp[ni][r] =
              (Kb[(size_t)(lhi * 4 + r) * 1024 + jn + ni * 16 + l16] - MREF) * LOG2E;
    }

    // QK^T: S[q=16 rows of wave][64 cols]
    f32x4 accS[4] = {};
#pragma unroll
    for (int ks = 0; ks < 2; ++ks) {
#pragma unroll
      for (int ni = 0; ni < 4; ++ni) {
        int row = ni * 16 + l16;
        bf16x8 kf = *(const bf16x8*)&Ks[cur][row * 64 + (((ks * 4 + lhi) ^ (row & 7)) << 3)];
        accS[ni] = __builtin_amdgcn_mfma_f32_16x16x32_bf16(
            ks ? qf1 : qf0, kf, accS[ni], 0, 0, 0);
      }
    }

    // fixed-reference softmax: e = exp2(S*log2e + (K-M)*log2e), masked cols -> 0
#pragma unroll
    for (int ni = 0; ni < 4; ++ni) {
      bool valid = (j0 + ni * 16 + l16) < nc;
#pragma unroll
      for (int r = 0; r < 4; ++r) {
        float e = __builtin_amdgcn_exp2f(fmaf(accS[ni][r], LOG2E, kvc[ni][r]));
        e = valid ? e : 0.f;
        lsum[r] += e;
        int prow = w * 16 + lhi * 4 + r;
        int col = ni * 16 + l16;
        Ps[prow * 64 + ((((col >> 3) ^ (prow & 7)) << 3) | (col & 7))] = f2bf(e);
      }
    }

    // PV: O[16 q][64 d] += P[16 q][64 k] @ Vt[d][k]^T  (Ps rows wave-private)
#pragma unroll
    for (int ks = 0; ks < 2; ++ks) {
      int prow = w * 16 + l16;
      bf16x8 pf = *(const bf16x8*)&Ps[prow * 64 + (((ks * 4 + lhi) ^ (prow & 7)) << 3)];
#pragma unroll
      for (int ni = 0; ni < 4; ++ni) {
        int vrow = ni * 16 + l16;
        bf16x8 vf = *(const bf16x8*)&Vs[cur][vrow * 64 + (((ks * 4 + lhi) ^ (vrow & 7)) << 3)];
        accO[ni] = __builtin_amdgcn_mfma_f32_16x16x32_bf16(pf, vf, accO[ni], 0, 0, 0);
      }
    }
  }

  // one-time denominator reduce over the 16-lane col group
#pragma unroll
  for (int r = 0; r < 4; ++r) {
    lsum[r] += __shfl_xor(lsum[r], 1);
    lsum[r] += __shfl_xor(lsum[r], 2);
    lsum[r] += __shfl_xor(lsum[r], 4);
    lsum[r] += __shfl_xor(lsum[r], 8);
  }

  if (final_out) {
    // epilogue: direct output (vmb values only needed for boundary rows)
#pragma unroll
    for (int ni = 0; ni < 4; ++ni) {
#pragma unroll
      for (int r = 0; r < 4; ++r) {
        int row = row0 + w * 16 + lhi * 4 + r;
        int d = ni * 16 + l16;
        short ov;
        if (row < nc) ov = f2bf(accO[ni][r] * (1.f / lsum[r]));
        else ov = vmb[bh * 64 + d];
        o[((size_t)(b * 1024 + row)) * 256 + hh * 64 + d] = ov;
      }
    }
  } else {
    // write fp32 partials; combine kernel sums over splits (fixed order)
    float* po = pO + (((size_t)sp * 64 + bh) * 16 + qt) * 4096;
#pragma unroll
    for (int ni = 0; ni < 4; ++ni)
#pragma unroll
      for (int r = 0; r < 4; ++r)
        po[(w * 16 + lhi * 4 + r) * 64 + ni * 16 + l16] = accO[ni][r];
    if (l16 == 0) {
      float* pl = pL + (((size_t)sp * 64 + bh) * 16 + qt) * 64;
#pragma unroll
      for (int r = 0; r < 4; ++r) pl[w * 16 + lhi * 4 + r] = lsum[r];
    }
    // mean-fill rows >= nc handled once (split covering jstart==0)
    if (sp == 0) {
      for (int idx = t; idx < 4096; idx += 256) {
        int r = idx >> 6, d = idx & 63;
        int row = row0 + r;
        if (row >= nc)
          o[((size_t)(b * 1024 + row)) * 256 + hh * 64 + d] = vmb[bh * 64 + d];
      }
    }
  }
}

// ---------------- combine split-K partials -> bf16 output ----------------
__global__ __launch_bounds__(256)
void fattn_combine(const float* __restrict__ pO, const float* __restrict__ pL,
                   const int* __restrict__ n1, const int* __restrict__ n2,
                   short* __restrict__ o, int tiles_per_split) {
  int bh = blockIdx.y, b = bh >> 2, hh = bh & 3;
  int qt = blockIdx.x;
  int row0 = qt * 64;
  int nc = n1[b] * n2[b];
  if (row0 >= nc) return;
  int ntiles = (nc + 63) >> 6;
  int nsp = (ntiles + tiles_per_split - 1) / tiles_per_split;
  if (nsp < 2) return;  // fattn wrote final output

  int t = threadIdx.x;
  int q = t >> 2, ds = (t & 3) * 16;
  int row = row0 + q;
  if (row >= nc) return;

  const size_t spstrideO = (size_t)64 * 16 * 4096;
  const size_t spstrideL = (size_t)64 * 16 * 64;
  const float* baseO = pO + ((size_t)bh * 16 + qt) * 4096 + q * 64 + ds;
  const float* baseL = pL + ((size_t)bh * 16 + qt) * 64 + q;

  f32x4 s[4] = {};
  float L = 0.f;
  for (int sp = 0; sp < nsp; ++sp) {
    const float* p = baseO + sp * spstrideO;
#pragma unroll
    for (int i = 0; i < 4; ++i) s[i] += *(const f32x4*)(p + i * 4);
    L += baseL[sp * spstrideL];
  }
  float rl = 1.f / L;
  short* op = o + ((size_t)(b * 1024 + row)) * 256 + hh * 64 + ds;
#pragma unroll
  for (int i = 0; i < 4; ++i) {
    short4 ov;
    ov.x = f2bf(s[i][0] * rl);
    ov.y = f2bf(s[i][1] * rl);
    ov.z = f2bf(s[i][2] * rl);
    ov.w = f2bf(s[i][3] * rl);
    *(short4*)(op + i * 4) = ov;
  }
}

// ---------------- fused proj GEMM + residual + LayerNorm2 ----------------
__global__ __launch_bounds__(256)
void proj_ln_mfma(const short* __restrict__ A, const short* __restrict__ Bw,
                  const float* __restrict__ bias, const float* __restrict__ resid,
                  const float* __restrict__ g2, const float* __restrict__ b2,
                  float* __restrict__ Cf, short* __restrict__ h2) {
  __shared__ __align__(16) short As[2][64 * 64];    // 16 KB
  __shared__ __align__(16) short Bs[2][256 * 64];   // 64 KB
  int t = threadIdx.x;
  int w = t >> 6, lane = t & 63;
  int l16 = lane & 15, lhi = lane >> 4;
  int m0 = blockIdx.x * 64;
  constexpr int Kd = 256;
  f32x4 acc[4][4] = {};

  // prologue: stage tile 0
#pragma unroll
  for (int i = 0; i < 2; ++i) {
    int cc = i * 256 + t;
    int r = cc >> 3, sl = cc & 7, ssl = sl ^ (r & 7);
    GLDS(A + (size_t)(m0 + r) * Kd + ssl * 8, &As[0][cc * 8]);
  }
#pragma unroll
  for (int i = 0; i < 8; ++i) {
    int cc = i * 256 + t;
    int r = cc >> 3, sl = cc & 7, ssl = sl ^ (r & 7);
    GLDS(Bw + (size_t)r * Kd + ssl * 8, &Bs[0][cc * 8]);
  }

  int cur = 0;
  for (int k0 = 0; k0 < Kd; k0 += 64, cur ^= 1) {
    asm volatile("s_waitcnt vmcnt(0)" ::: "memory");
    __syncthreads();
    int kn = k0 + 64;
    if (kn < Kd) {
      int nxt = cur ^ 1;
#pragma unroll
      for (int i = 0; i < 2; ++i) {
        int cc = i * 256 + t;
        int r = cc >> 3, sl = cc & 7, ssl = sl ^ (r & 7);
        GLDS(A + (size_t)(m0 + r) * Kd + kn + ssl * 8, &As[nxt][cc * 8]);
      }
#pragma unroll
      for (int i = 0; i < 8; ++i) {
        int cc = i * 256 + t;
        int r = cc >> 3, sl = cc & 7, ssl = sl ^ (r & 7);
        GLDS(Bw + (size_t)r * Kd + kn + ssl * 8, &Bs[nxt][cc * 8]);
      }
    }
#pragma unroll
    for (int ks = 0; ks < 2; ++ks) {
      bf16x8 af[4], bg[4];
#pragma unroll
      for (int mi = 0; mi < 4; ++mi) {
        int row = mi * 16 + l16;
        af[mi] = *(const bf16x8*)&As[cur][row * 64 + ((ks * 32 + lhi * 8) ^ ((row & 7) << 3))];
      }
#pragma unroll
      for (int ni = 0; ni < 4; ++ni) {
        int row = w * 64 + ni * 16 + l16;
        bg[ni] = *(const bf16x8*)&Bs[cur][row * 64 + ((ks * 32 + lhi * 8) ^ ((row & 7) << 3))];
      }
#pragma unroll
      for (int mi = 0; mi < 4; ++mi)
#pragma unroll
        for (int ni = 0; ni < 4; ++ni)
          acc[mi][ni] = __builtin_amdgcn_mfma_f32_16x16x32_bf16(
              af[mi], bg[ni], acc[mi][ni], 0, 0, 0);
    }
  }

  // epilogue: v = acc + bias + resid; write fp32 out; keep v in acc
  float bv[4], gl[4], bl[4];
#pragma unroll
  for (int ni = 0; ni < 4; ++ni) {
    int n = w * 64 + ni * 16 + l16;
    bv[ni] = bias[n];
    gl[ni] = g2[n];
    bl[ni] = b2[n];
  }
#pragma unroll
  for (int mi = 0; mi < 4; ++mi)
#pragma unroll
    for (int ni = 0; ni < 4; ++ni) {
      int n = w * 64 + ni * 16 + l16;
#pragma unroll
      for (int r = 0; r < 4; ++r) {
        int m = m0 + mi * 16 + lhi * 4 + r;
        size_t idx = (size_t)m * 256 + n;
        float v = acc[mi][ni][r] + bv[ni] + resid[idx];
        acc[mi][ni][r] = v;
        Cf[idx] = v;
      }
    }

  // per-row stats: thread-local over ni, shuffle over l16, LDS across waves
  float s[4][4], qq[4][4];
#pragma unroll
  for (int mi = 0; mi < 4; ++mi)
#pragma unroll
    for (int r = 0; r < 4; ++r) {
      float a0 = acc[mi][0][r], a1 = acc[mi][1][r];
      float a2 = acc[mi][2][r], a3 = acc[mi][3][r];
      s[mi][r] = a0 + a1 + a2 + a3;
      qq[mi][r] = a0 * a0 + a1 * a1 + a2 * a2 + a3 * a3;
    }
#pragma unroll
  for (int off = 1; off <= 8; off <<= 1)
#pragma unroll
    for (int mi = 0; mi < 4; ++mi)
#pragma unroll
      for (int r = 0; r < 4; ++r) {
        s[mi][r] += __shfl_xor(s[mi][r], off);
        qq[mi][r] += __shfl_xor(qq[mi][r], off);
      }

  __syncthreads();  // all waves done reading As/Bs; safe to alias As
  float* partS = (float*)&As[0][0];   // [4 waves][64 rows]
  float* partQ = partS + 256;
  if (l16 == 0) {
#pragma unroll
    for (int mi = 0; mi < 4; ++mi)
#pragma unroll
      for (int r = 0; r < 4; ++r) {
        int row = mi * 16 + lhi * 4 + r;
        partS[w * 64 + row] = s[mi][r];
        partQ[w * 64 + row] = qq[mi][r];
      }
  }
  __syncthreads();

#pragma unroll
  for (int mi = 0; mi < 4; ++mi)
#pragma unroll
    for (int r = 0; r < 4; ++r) {
      int row = mi * 16 + lhi * 4 + r;
      float S = partS[row] + partS[64 + row] + partS[128 + row] + partS[192 + row];
      float Q = partQ[row] + partQ[64 + row] + partQ[128 + row] + partQ[192 + row];
      float mean = S * (1.f / 256.f);
      float var = Q * (1.f / 256.f) - mean * mean;
      float inv = rsqrtf(var + EPSV);
      int m = m0 + row;
#pragma unroll
      for (int ni = 0; ni < 4; ++ni) {
        int n = w * 64 + ni * 16 + l16;
        h2[(size_t)m * 256 + n] =
            f2bf((acc[mi][ni][r] - mean) * inv * gl[ni] + bl[ni]);
      }
    }
}

// ---------------- bf16 MFMA GEMM 128x128, 2-phase pipelined ----------------
template <bool GELU, bool RES, bool OUTF, bool OUTB>
__global__ __launch_bounds__(256)
void gemm_mfma(const short* __restrict__ A, const short* __restrict__ Bw,
               const float* __restrict__ bias, const float* __restrict__ resid,
               float* __restrict__ Cf, short* __restrict__ Cb,
               int M, int Nd, int Kd) {
  __shared__ __align__(16) short As[2][128 * 64];
  __shared__ __align__(16) short Bs[2][128 * 64];
  int t = threadIdx.x;
  int w = t >> 6, lane = t & 63;
  int wm = w >> 1, wn = w & 1;
  int l16 = lane & 15, lhi = lane >> 4;
  int m0 = blockIdx.y * 128, n0 = blockIdx.x * 128;
  f32x4 acc[4][4] = {};

  // prologue: stage tile 0 into buf 0
#pragma unroll
  for (int i = 0; i < 4; ++i) {
    int cc = i * 256 + t;
    int r = cc >> 3, sl = cc & 7, ssl = sl ^ (r & 7);
    GLDS(A + (size_t)(m0 + r) * Kd + ssl * 8, &As[0][cc * 8]);
    GLDS(Bw + (size_t)(n0 + r) * Kd + ssl * 8, &Bs[0][cc * 8]);
  }

  int cur = 0;
  for (int k0 = 0; k0 < Kd; k0 += 64, cur ^= 1) {
    asm volatile("s_waitcnt vmcnt(0)" ::: "memory");
    __syncthreads();  // tile k ready; buf[cur^1] free
    int kn = k0 + 64;
    if (kn < Kd) {
      int nxt = cur ^ 1;
#pragma unroll
      for (int i = 0; i < 4; ++i) {
        int cc = i * 256 + t;
        int r = cc >> 3, sl = cc & 7, ssl = sl ^ (r & 7);
        GLDS(A + (size_t)(m0 + r) * Kd + kn + ssl * 8, &As[nxt][cc * 8]);
        GLDS(Bw + (size_t)(n0 + r) * Kd + kn + ssl * 8, &Bs[nxt][cc * 8]);
      }
    }
#pragma unroll
    for (int ks = 0; ks < 2; ++ks) {
      bf16x8 af[4], bg[4];
#pragma unroll
      for (int mi = 0; mi < 4; ++mi) {
        int row = wm * 64 + mi * 16 + l16;
        af[mi] = *(const bf16x8*)&As[cur][row * 64 + ((ks * 32 + lhi * 8) ^ ((row & 7) << 3))];
      }
#pragma unroll
      for (int ni = 0; ni < 4; ++ni) {
        int row = wn * 64 + ni * 16 + l16;
        bg[ni] = *(const bf16x8*)&Bs[cur][row * 64 + ((ks * 32 + lhi * 8) ^ ((row & 7) << 3))];
      }
#pragma unroll
      for (int mi = 0; mi < 4; ++mi)
#pragma unroll
        for (int ni = 0; ni < 4; ++ni)
          acc[mi][ni] = __builtin_amdgcn_mfma_f32_16x16x32_bf16(
              af[mi], bg[ni], acc[mi][ni], 0, 0, 0);
    }
  }
#pragma unroll
  for (int mi = 0; mi < 4; ++mi) {
    int rbase = m0 + wm * 64 + mi * 16 + lhi * 4;
#pragma unroll
    for (int ni = 0; ni < 4; ++ni) {
      int n = n0 + wn * 64 + ni * 16 + l16;
      float bv = bias[n];
#pragma unroll
      for (int r = 0; r < 4; ++r) {
        int m = rbase + r;
        float v = acc[mi][ni][r] + bv;
        if (GELU) v = gelu_fast(v);
        size_t idx = (size_t)m * Nd + n;
        if (RES) v += resid[idx];
        if (OUTF) Cf[idx] = v;
        if (OUTB) Cb[idx] = f2bf(v);
      }
    }
  }
}

// ---------------- bf16 MFMA GEMM 64x128, 2-phase pipelined ----------------
template <bool GELU, bool RES, bool OUTF, bool OUTB>
__global__ __launch_bounds__(256)
void gemm64_mfma(const short* __restrict__ A, const short* __restrict__ Bw,
                 const float* __restrict__ bias, const float* __restrict__ resid,
                 float* __restrict__ Cf, short* __restrict__ Cb,
                 int M, int Nd, int Kd) {
  __shared__ __align__(16) short As[2][64 * 64];
  __shared__ __align__(16) short Bs[2][128 * 64];
  int t = threadIdx.x;
  int w = t >> 6, lane = t & 63;
  int l16 = lane & 15, lhi = lane >> 4;
  int m0 = blockIdx.y * 64, n0 = blockIdx.x * 128;
  f32x4 acc[4][2] = {};

  // prologue: stage tile 0 into buf 0
#pragma unroll
  for (int i = 0; i < 2; ++i) {
    int cc = i * 256 + t;
    int r = cc >> 3, sl = cc & 7, ssl = sl ^ (r & 7);
    GLDS(A + (size_t)(m0 + r) * Kd + ssl * 8, &As[0][cc * 8]);
  }
#pragma unroll
  for (int i = 0; i < 4; ++i) {
    int cc = i * 256 + t;
    int r = cc >> 3, sl = cc & 7, ssl = sl ^ (r & 7);
    GLDS(Bw + (size_t)(n0 + r) * Kd + ssl * 8, &Bs[0][cc * 8]);
  }

  int cur = 0;
  for (int k0 = 0; k0 < Kd; k0 += 64, cur ^= 1) {
    asm volatile("s_waitcnt vmcnt(0)" ::: "memory");
    __syncthreads();  // tile k ready; buf[cur^1] free
    int kn = k0 + 64;
    if (kn < Kd) {
      int nxt = cur ^ 1;
#pragma unroll
      for (int i = 0; i < 2; ++i) {
        int cc = i * 256 + t;
        int r = cc >> 3, sl = cc & 7, ssl = sl ^ (r & 7);
        GLDS(A + (size_t)(m0 + r) * Kd + kn + ssl * 8, &As[nxt][cc * 8]);
      }
#pragma unroll
      for (int i = 0; i < 4; ++i) {
        int cc = i * 256 + t;
        int r = cc >> 3, sl = cc & 7, ssl = sl ^ (r & 7);
        GLDS(Bw + (size_t)(n0 + r) * Kd + kn + ssl * 8, &Bs[nxt][cc * 8]);
      }
    }
#pragma unroll
    for (int ks = 0; ks < 2; ++ks) {
      bf16x8 af[4], bg[2];
#pragma unroll
      for (int mi = 0; mi < 4; ++mi) {
        int row = mi * 16 + l16;
        af[mi] = *(const bf16x8*)&As[cur][row * 64 + ((ks * 32 + lhi * 8) ^ ((row & 7) << 3))];
      }
#pragma unroll
      for (int ni = 0; ni < 2; ++ni) {
        int row = w * 32 + ni * 16 + l16;
        bg[ni] = *(const bf16x8*)&Bs[cur][row * 64 + ((ks * 32 + lhi * 8) ^ ((row & 7) << 3))];
      }
#pragma unroll
      for (int mi = 0; mi < 4; ++mi)
#pragma unroll
        for (int ni = 0; ni < 2; ++ni)
          acc[mi][ni] = __builtin_amdgcn_mfma_f32_16x16x32_bf16(
              af[mi], bg[ni], acc[mi][ni], 0, 0, 0);
    }
  }
#pragma unroll
  for (int mi = 0; mi < 4; ++mi) {
    int rbase = m0 + mi * 16 + lhi * 4;
#pragma unroll
    for (int ni = 0; ni < 2; ++ni) {
      int n = n0 + w * 32 + ni * 16 + l16;
      float bv = bias[n];
#pragma unroll
      for (int r = 0; r < 4; ++r) {
        int m = rbase + r;
        float v = acc[mi][ni][r] + bv;
        if (GELU) v = gelu_fast(v);
        size_t idx = (size_t)m * Nd + n;
        if (RES) v += resid[idx];
        if (OUTF) Cf[idx] = v;
        if (OUTB) Cb[idx] = f2bf(v);
      }
    }
  }
}

extern "C" void kernel_launch(void* const* d_in, const int* in_sizes, int n_in,
                              void* d_out, int out_size, void* d_ws, size_t ws_size,
                              hipStream_t stream) {
  const float* x      = (const float*)d_in[0];
  const float* Kmat   = (const float*)d_in[1];
  const int*   n1     = (const int*)d_in[2];
  const int*   n2     = (const int*)d_in[3];
  const float* qkv_w  = (const float*)d_in[4];
  const float* qkv_b  = (const float*)d_in[5];
  const float* proj_w = (const float*)d_in[6];
  const float* proj_b = (const float*)d_in[7];
  const float* ln1_g  = (const float*)d_in[8];
  const float* ln1_b  = (const float*)d_in[9];
  const float* ln2_g  = (const float*)d_in[10];
  const float* ln2_b  = (const float*)d_in[11];
  const float* fc1_w  = (const float*)d_in[12];
  const float* fc1_b  = (const float*)d_in[13];
  const float* fc2_w  = (const float*)d_in[14];
  const float* fc2_b  = (const float*)d_in[15];
  float* out = (float*)d_out;

  char* ws = (char*)d_ws;
  constexpr size_t MB = 1024 * 1024;
  // layout:
  //  [0,8): hb bf16 (LN1 out -> obuf attn out)
  //  [8,24): qkp bf16 (qpk at 8, kpk at 16); [24,32): vt bf16 [bh][d][row]
  //  [8,40): m1 bf16 (fc1 out; overlays qkp/vt AFTER attention)
  //  [40]: vmb ; [41..45): bf16 weights
  //  [48,116): split-K partial O fp32 (dead after combine) -> hb2 (LN2 out)
  //  [116,117): partial L fp32
  short* hb    = (short*)ws;
  short* qkp   = (short*)(ws + 8 * MB);
  short* vtp   = (short*)(ws + 24 * MB);
  short* m1    = (short*)(ws + 8 * MB);
  short* vmb   = (short*)(ws + 40 * MB);
  short* wqkv  = (short*)(ws + 41 * MB);
  short* wproj = (short*)(ws + 42 * MB);
  short* wfc1  = (short*)(ws + 43 * MB);
  short* wfc2  = (short*)(ws + 44 * MB);
  float* pO    = (float*)(ws + 48 * MB);
  float* pL    = (float*)(ws + 116 * MB);
  short* hb2   = (short*)(ws + 48 * MB);  // reuses pO region (dead by proj time)
  short* obuf  = hb;
  short* qpk   = qkp;
  short* kpk   = qkp + 4194304;

  const bool split = ws_size >= (size_t)118 * MB;

  // 0+1) weights -> bf16 AND h = LN1(x) -> bf16 (single launch)
  prep_kernel<<<dim3(768 + Mrows / 4), 256, 0, stream>>>(
      qkv_w, wqkv, proj_w, wproj, fc1_w, wfc1, fc2_w, wfc2,
      x, ln1_g, ln1_b, hb);
  // 2) qkv GEMM -> packed bf16 q (x0.125), k [bh][row][d]; v^T [bh][d][row]
  qkv_mfma<<<dim3(6, 128), 256, 0, stream>>>(hb, wqkv, qkv_b, qkp, vtp);
  // 3) per-(b,h) mean of v
  vmean_kernel<<<dim3(Bc * Hh), 256, 0, stream>>>(vtp, vmb);
  // 4) MFMA flash attention -> obuf bf16 [B,N,C] (split-K caps serial chain at 4)
  if (split) {
    fattn_mfma<<<dim3(Nn / 64, Bc * Hh, 4), 256, 0, stream>>>(
        qpk, kpk, vtp, Kmat, n1, n2, vmb, obuf, pO, pL, 4);
    fattn_combine<<<dim3(Nn / 64, Bc * Hh), 256, 0, stream>>>(
        pO, pL, n1, n2, obuf, 4);
  } else {
    fattn_mfma<<<dim3(Nn / 64, Bc * Hh, 1), 256, 0, stream>>>(
        qpk, kpk, vtp, Kmat, n1, n2, vmb, obuf, pO, pL, 16);
  }
  // 5+6) out = x + obuf @ proj_w^T + proj_b (fp32) AND hb2 = LN2(out) bf16, fused
  proj_ln_mfma<<<dim3(256), 256, 0, stream>>>(
      obuf, wproj, proj_b, x, ln2_g, ln2_b, out, hb2);
  // 7) m1 = GELU(hb2 @ fc1_w^T + fc1_b) -> bf16
  gemm_mfma<true, false, false, true><<<dim3(8, 128), 256, 0, stream>>>(
      hb2, wfc1, fc1_b, nullptr, nullptr, m1, Mrows, 1024, 256);
  // 8) out = out + m1 @ fc2_w^T + fc2_b (in-place residual) [64-row tiles]
  gemm64_mfma<false, true, true, false><<<dim3(2, 256), 256, 0, stream>>>(
      m1, wfc2, fc2_b, out, out, nullptr, Mrows, 256, 1024);
}